// Round 5
// baseline (1871.296 us; speedup 1.0000x reference)
//
#include <hip/hip_runtime.h>

#define BB 4
#define HH 8
#define LL 8192
#define NN (BB*LL)
#define DDIM 32
#define MM 128
#define NR (NN*HH)          // 262144 (n,h) rows

// ws layout (float offsets)
#define CTXR_OFF 0                          // 32*8*128*4 = 131072
#define KSUMR_OFF (CTXR_OFF + 32*8*MM*4)    // 4096
#define VSUM_OFF  (KSUMR_OFF + 32*MM)       // 1024
#define GMAX_OFF  (VSUM_OFF + 32*32)        // 1
#define RMAX_OFF  (GMAX_OFF + 1)            // NR
#define DIAG_OFF  (RMAX_OFF + NR)           // NR
#define ZERO_FLOATS (GMAX_OFF + 1)

#define DN 0.42044820762685725f             // 32^-0.25
#define RATIO 0.08838834764831845f          // 128^-0.5
#define EPSF 1e-4f

// ------- k1: fused features + dd + rowmax/diag + exp(dd-diag)*v accumulation
// Staging: each thread owns exactly ONE float4 per 16-row batch, address
// advances by a constant stride; LDS double-buffered so the load for batch
// s+1 is in flight during batch s's compute.
__global__ __launch_bounds__(256, 4) void k_ctx1(const float* __restrict__ kk0,
                                                 const float* __restrict__ kk1,
                                                 const float* __restrict__ v0,
                                                 const float* __restrict__ v1,
                                                 const float* __restrict__ w,
                                                 float* __restrict__ ws) {
    __shared__ float sv[2][16][64];  // [0:32) feats*DN, [32:64) v packed per-c float4
    __shared__ float ddl[16][132];
    __shared__ float sdiag[16];
    __shared__ float bred[4];
    const int tid = threadIdx.x;
    const int m = tid & 127, half = tid >> 7;
    float wreg[DDIM];
    {
        const float4* w4 = (const float4*)(w + m*DDIM);
#pragma unroll
        for (int q = 0; q < 8; ++q) {
            const float4 t = w4[q];
            wreg[q*4+0]=t.x; wreg[q*4+1]=t.y; wreg[q*4+2]=t.z; wreg[q*4+3]=t.w;
        }
    }
    const int bh = blockIdx.x >> 5, chunk = blockIdx.x & 31;
    const int b = bh >> 3, h = bh & 7;
    const int nb0_0 = b*LL + chunk*256;
    // ---- per-thread staging descriptor (constant across batches) ----
    const float* gptr;
    int gstep, lds_lr, lo0, lo1, lo2, lo3;
    bool isfeat;
    if (tid < 32) {                    // k0 feats: 32 float4
        const int lr = tid >> 1, q = tid & 1;
        gptr = kk0 + (size_t)(nb0_0 + lr)*64 + h*8 + q*4;
        gstep = 16*64; lds_lr = lr; lo0 = q*4; lo1 = lo2 = lo3 = 0; isfeat = true;
    } else if (tid < 128) {            // k1 feats: 96 float4
        const int j = tid - 32, lr = j/6, r6 = j - lr*6;
        gptr = kk1 + (size_t)(nb0_0 + lr)*192 + h*24 + r6*4;
        gstep = 16*192; lds_lr = lr; lo0 = 8 + r6*4; lo1 = lo2 = lo3 = 0; isfeat = true;
    } else if (tid < 160) {            // v0: 32 float4 -> strided LDS (jj=0 slots)
        const int j = tid - 128, lr = j >> 1, q = j & 1;
        gptr = v0 + (size_t)(nb0_0 + lr)*64 + h*8 + q*4;
        gstep = 16*64; lds_lr = lr;
        lo0 = 32 + (q*4+0)*4; lo1 = 32 + (q*4+1)*4;
        lo2 = 32 + (q*4+2)*4; lo3 = 32 + (q*4+3)*4; isfeat = false;
    } else {                           // v1: 96 float4 -> scattered (jj=1..3 slots)
        const int j = tid - 160, lr = j/6, r6 = j - lr*6;
        gptr = v1 + (size_t)(nb0_0 + lr)*192 + h*24 + r6*4;
        gstep = 16*192; lds_lr = lr;
        const int e0 = r6*4;
        lo0 = 32 + ((e0+0)/3)*4 + 1 + (e0+0)%3;
        lo1 = 32 + ((e0+1)/3)*4 + 1 + (e0+1)%3;
        lo2 = 32 + ((e0+2)/3)*4 + 1 + (e0+2)%3;
        lo3 = 32 + ((e0+3)/3)*4 + 1 + (e0+3)%3; isfeat = false;
    }
    // ---- prologue: stage batch 0 into sv[0] ----
    {
        float4 val = *(const float4*)gptr; gptr += gstep;
        if (isfeat) {
            val.x *= DN; val.y *= DN; val.z *= DN; val.w *= DN;
            *(float4*)&sv[0][lds_lr][lo0] = val;
        } else {
            sv[0][lds_lr][lo0] = val.x; sv[0][lds_lr][lo1] = val.y;
            sv[0][lds_lr][lo2] = val.z; sv[0][lds_lr][lo3] = val.w;
        }
    }
    float acc[16];
#pragma unroll
    for (int i = 0; i < 16; ++i) acc[i] = 0.f;
    float ksum_acc = 0.f, vsum_acc = 0.f;
    float blockmax = -3.4e38f;
    float* rmaxg = ws + RMAX_OFF;
    float* diagg = ws + DIAG_OFF;
    __syncthreads();
    int cur = 0;
    for (int s = 0; s < 16; ++s) {
        const int nb0 = nb0_0 + s*16;
        // prefetch batch s+1 (latency hides under this batch's compute)
        float4 nval;
        if (s < 15) { nval = *(const float4*)gptr; gptr += gstep; }
        // diag: 16 lanes per row, shuffle reduce
        {
            const int row = tid >> 4, t16 = tid & 15;
            const float a = sv[cur][row][2*t16], b2 = sv[cur][row][2*t16+1];
            float ss = a*a + b2*b2;
            ss += __shfl_xor(ss, 1); ss += __shfl_xor(ss, 2);
            ss += __shfl_xor(ss, 4); ss += __shfl_xor(ss, 8);
            if (t16 == 0) { sdiag[row] = 0.5f*ss; diagg[(nb0+row)*8 + h] = 0.5f*ss; }
        }
        // dd for this half's 8 rows -> ddl
#pragma unroll
        for (int r8 = 0; r8 < 8; ++r8) {
            const int row = half*8 + r8;
            const float4* f4 = (const float4*)&sv[cur][row][0];
            float dd = 0.f;
#pragma unroll
            for (int q = 0; q < 8; ++q) {
                const float4 qv = f4[q];
                dd = fmaf(qv.x, wreg[q*4+0], dd);
                dd = fmaf(qv.y, wreg[q*4+1], dd);
                dd = fmaf(qv.z, wreg[q*4+2], dd);
                dd = fmaf(qv.w, wreg[q*4+3], dd);
            }
            ddl[row][m] = dd;
        }
        __syncthreads();
        // accumulate: EVERY thread, ALL 16 rows
#pragma unroll
        for (int row = 0; row < 16; ++row) {
            const float kp = __expf(ddl[row][m] - sdiag[row]);
            ksum_acc += kp;
            const float4* vv = (const float4*)&sv[cur][row][32];
#pragma unroll
            for (int cc = 0; cc < 4; ++cc) {
                const float4 vq = vv[half*4 + cc];
                acc[cc*4+0] = fmaf(kp, vq.x, acc[cc*4+0]);
                acc[cc*4+1] = fmaf(kp, vq.y, acc[cc*4+1]);
                acc[cc*4+2] = fmaf(kp, vq.z, acc[cc*4+2]);
                acc[cc*4+3] = fmaf(kp, vq.w, acc[cc*4+3]);
            }
        }
        if (tid < 32) {
#pragma unroll
            for (int lr = 0; lr < 16; ++lr) vsum_acc += sv[cur][lr][32 + tid];
        }
        // rowmax over m
        if (tid < 128) {
            const int row = tid >> 3, mo = tid & 7;
            float mx = -3.4e38f;
#pragma unroll
            for (int q = 0; q < 4; ++q) {
                const float4 v4 = *(const float4*)&ddl[row][mo*16 + q*4];
                mx = fmaxf(mx, fmaxf(fmaxf(v4.x, v4.y), fmaxf(v4.z, v4.w)));
            }
            mx = fmaxf(mx, __shfl_xor(mx, 1));
            mx = fmaxf(mx, __shfl_xor(mx, 2));
            mx = fmaxf(mx, __shfl_xor(mx, 4));
            if (mo == 0) rmaxg[(nb0+row)*8 + h] = mx;
            blockmax = fmaxf(blockmax, mx);
        }
        // write prefetched batch to the other buffer
        if (s < 15) {
            const int nxt = cur ^ 1;
            if (isfeat) {
                nval.x *= DN; nval.y *= DN; nval.z *= DN; nval.w *= DN;
                *(float4*)&sv[nxt][lds_lr][lo0] = nval;
            } else {
                sv[nxt][lds_lr][lo0] = nval.x; sv[nxt][lds_lr][lo1] = nval.y;
                sv[nxt][lds_lr][lo2] = nval.z; sv[nxt][lds_lr][lo3] = nval.w;
            }
        }
        __syncthreads();
        cur ^= 1;
    }
    float* ctxr = ws + CTXR_OFF;
#pragma unroll
    for (int cc = 0; cc < 4; ++cc) {
        const int c = half*4 + cc;
#pragma unroll
        for (int j = 0; j < 4; ++j)
            atomicAdd(&ctxr[((bh*8 + c)*MM + m)*4 + j], acc[cc*4+j]);
    }
    if (half == 0) atomicAdd(ws + KSUMR_OFF + bh*MM + m, ksum_acc);
    if (tid < 32)  atomicAdd(ws + VSUM_OFF + bh*32 + tid, vsum_acc);
    float bm = blockmax;
#pragma unroll
    for (int off = 32; off; off >>= 1) bm = fmaxf(bm, __shfl_xor(bm, off, 64));
    if ((tid & 63) == 0) bred[tid >> 6] = bm;
    __syncthreads();
    if (tid == 0) {
        const float g = fmaxf(fmaxf(bred[0], bred[1]), fmaxf(bred[2], bred[3]));
        unsigned u = __float_as_uint(g);
        u = (u & 0x80000000u) ? ~u : (u | 0x80000000u);
        atomicMax((unsigned*)(ws + GMAX_OFF), u);
    }
}

// ------- k3: finalize ctx/ksum, Qp from fresh k-gather, D_inv, readout -----
__global__ __launch_bounds__(256) void k_out(const float* __restrict__ kk0,
                                             const float* __restrict__ kk1,
                                             const float* __restrict__ w,
                                             const float* __restrict__ ws,
                                             float* __restrict__ out) {
    __shared__ float ctx_s[8*516];
    __shared__ float qpT[128*68];     // [m][row<64], pad 68 (b128-aligned)
    __shared__ float sf[64][36];      // feats*DN, pad 36 keeps float4 alignment
    __shared__ float sdiag[64], srmax[64], dinv[64], ksl[128];
    const int tid = threadIdx.x;
    const int m = tid & 127, half = tid >> 7;
    float wreg[DDIM];
    {
        const float4* w4 = (const float4*)(w + m*DDIM);
#pragma unroll
        for (int q = 0; q < 8; ++q) {
            const float4 t = w4[q];
            wreg[q*4+0]=t.x; wreg[q*4+1]=t.y; wreg[q*4+2]=t.z; wreg[q*4+3]=t.w;
        }
    }
    const int bh = blockIdx.x >> 6, blk = blockIdx.x & 63;
    const int b = bh >> 3, h = bh & 7;
    const unsigned gu = *((const unsigned*)(ws + GMAX_OFF));
    const float gm = (gu & 0x80000000u) ? __uint_as_float(gu & 0x7fffffffu)
                                        : __uint_as_float(~gu);
    const float alpha = __expf(-gm);
    const float* ctxr = ws + CTXR_OFF + bh*4096;
    const float* vsg  = ws + VSUM_OFF + bh*32;
    for (int g = tid; g < 4096; g += 256) {
        const int c = g >> 9, mm2 = (g >> 2) & 127, j = g & 3;
        ctx_s[c*516 + mm2*4 + j] = RATIO*(alpha*ctxr[g] + EPSF*vsg[c*4 + j]);
    }
    if (tid < 128) ksl[tid] = RATIO*(alpha*ws[KSUMR_OFF + bh*MM + tid] + EPSF*(float)LL);
    const float* rmaxg = ws + RMAX_OFF;
    const float* diagg = ws + DIAG_OFF;
    for (int tile = 0; tile < 2; ++tile) {
        const int lbase = blk*128 + tile*64;
        const int n0 = b*LL + lbase;
        __syncthreads();
        // stage 64 feature rows + diag/rmax
#pragma unroll
        for (int p = 0; p < 8; ++p) {
            const int i = tid + p*256;
            if (i < 512)       { const int lr = i >> 3, d = i & 7;
                                 sf[lr][d] = kk0[(n0+lr)*64 + h*8 + d] * DN; }
            else if (i < 2048) { const int jn = i - 512; const int lr = jn/24;
                                 const int d2 = jn - lr*24;
                                 sf[lr][8 + d2] = kk1[(n0+lr)*192 + h*24 + d2] * DN; }
        }
        if (tid < 64)       sdiag[tid]    = diagg[(n0+tid)*8 + h];
        else if (tid < 128) srmax[tid-64] = rmaxg[(n0+tid-64)*8 + h];
        __syncthreads();
        // phase A: Qp for 64 rows -> qpT
#pragma unroll
        for (int r4 = 0; r4 < 8; ++r4) {
            float q4[4];
#pragma unroll
            for (int k = 0; k < 4; ++k) {
                const int row = half*32 + r4*4 + k;
                const float4* f4 = (const float4*)&sf[row][0];
                float dd = 0.f;
#pragma unroll
                for (int q = 0; q < 8; ++q) {
                    const float4 qv = f4[q];
                    dd = fmaf(qv.x, wreg[q*4+0], dd);
                    dd = fmaf(qv.y, wreg[q*4+1], dd);
                    dd = fmaf(qv.z, wreg[q*4+2], dd);
                    dd = fmaf(qv.w, wreg[q*4+3], dd);
                }
                q4[k] = RATIO*(__expf(dd - sdiag[row] - srmax[row]) + EPSF);
            }
            *(float4*)&qpT[m*68 + half*32 + r4*4] = make_float4(q4[0],q4[1],q4[2],q4[3]);
        }
        __syncthreads();
        // phase B: D_inv
        {
            const int row = tid >> 2, mq = tid & 3;
            float ssum = 0.f;
#pragma unroll
            for (int i = 0; i < 32; ++i) {
                const int mm2 = mq*32 + i;
                ssum = fmaf(qpT[mm2*68 + row], ksl[mm2], ssum);
            }
            ssum += __shfl_xor(ssum, 1);
            ssum += __shfl_xor(ssum, 2);
            if (mq == 0) dinv[row] = 1.f/ssum;
        }
        __syncthreads();
        // phase C: out = (qp . ctx) * dinv, register-tiled
        {
            const int c = tid & 7, mh = (tid >> 3) & 1, rg = tid >> 4;
            float4 a0 = {0,0,0,0}, a1 = {0,0,0,0}, a2 = {0,0,0,0}, a3 = {0,0,0,0};
            const float4* cx = (const float4*)&ctx_s[c*516];
            const int mstart = mh*64;
#pragma unroll 8
            for (int i = 0; i < 64; ++i) {
                const int mm2 = mstart + i;
                const float4 cv = cx[mm2];
                const float4 qv = *(const float4*)&qpT[mm2*68 + rg*4];
                a0.x = fmaf(qv.x, cv.x, a0.x); a0.y = fmaf(qv.x, cv.y, a0.y);
                a0.z = fmaf(qv.x, cv.z, a0.z); a0.w = fmaf(qv.x, cv.w, a0.w);
                a1.x = fmaf(qv.y, cv.x, a1.x); a1.y = fmaf(qv.y, cv.y, a1.y);
                a1.z = fmaf(qv.y, cv.z, a1.z); a1.w = fmaf(qv.y, cv.w, a1.w);
                a2.x = fmaf(qv.z, cv.x, a2.x); a2.y = fmaf(qv.z, cv.y, a2.y);
                a2.z = fmaf(qv.z, cv.z, a2.z); a2.w = fmaf(qv.z, cv.w, a2.w);
                a3.x = fmaf(qv.w, cv.x, a3.x); a3.y = fmaf(qv.w, cv.y, a3.y);
                a3.z = fmaf(qv.w, cv.z, a3.z); a3.w = fmaf(qv.w, cv.w, a3.w);
            }
            a0.x += __shfl_xor(a0.x, 8); a0.y += __shfl_xor(a0.y, 8);
            a0.z += __shfl_xor(a0.z, 8); a0.w += __shfl_xor(a0.w, 8);
            a1.x += __shfl_xor(a1.x, 8); a1.y += __shfl_xor(a1.y, 8);
            a1.z += __shfl_xor(a1.z, 8); a1.w += __shfl_xor(a1.w, 8);
            a2.x += __shfl_xor(a2.x, 8); a2.y += __shfl_xor(a2.y, 8);
            a2.z += __shfl_xor(a2.z, 8); a2.w += __shfl_xor(a2.w, 8);
            a3.x += __shfl_xor(a3.x, 8); a3.y += __shfl_xor(a3.y, 8);
            a3.z += __shfl_xor(a3.z, 8); a3.w += __shfl_xor(a3.w, 8);
            const float4 s0 = mh ? a2 : a0;
            const float4 s1 = mh ? a3 : a1;
            const int lr0 = rg*4 + mh*2;
#pragma unroll
            for (int k = 0; k < 2; ++k) {
                const float4 sv4 = k ? s1 : s0;
                const int lr = lr0 + k;
                const float dv = dinv[lr];
                const int n = n0 + lr;
                const int base = n*64 + h*8 + c;
                out[base] = sv4.x * dv;
                float* o1 = out + NN*64 + base*3;
                o1[0] = sv4.y * dv;
                o1[1] = sv4.z * dv;
                o1[2] = sv4.w * dv;
            }
        }
    }
}

extern "C" void kernel_launch(void* const* d_in, const int* in_sizes, int n_in,
                              void* d_out, int out_size, void* d_ws, size_t ws_size,
                              hipStream_t stream) {
    const float* v0 = (const float*)d_in[0];
    const float* v1 = (const float*)d_in[1];
    const float* k0 = (const float*)d_in[2];
    const float* k1 = (const float*)d_in[3];
    const float* w  = (const float*)d_in[6];
    float* out = (float*)d_out;
    float* ws  = (float*)d_ws;
    hipMemsetAsync(ws, 0, (size_t)ZERO_FLOATS*sizeof(float), stream);
    k_ctx1<<<1024, 256, 0, stream>>>(k0, k1, v0, v1, w, ws);
    k_out <<<2048, 256, 0, stream>>>(k0, k1, w, ws, out);
}

// Round 6
// 782.303 us; speedup vs baseline: 2.3920x; 2.3920x over previous
//
#include <hip/hip_runtime.h>

#define BB 4
#define HH 8
#define LL 8192
#define NN (BB*LL)
#define DDIM 32
#define MM 128
#define NR (NN*HH)          // 262144 (n,h) rows

// ws layout (float offsets)
#define CTXR_OFF 0                          // 32*8*128*4 = 131072
#define KSUMR_OFF (CTXR_OFF + 32*8*MM*4)    // 4096
#define VSUM_OFF  (KSUMR_OFF + 32*MM)       // 1024
#define GMAX_OFF  (VSUM_OFF + 32*32)        // 1
#define RMAX_OFF  (GMAX_OFF + 1)            // NR
#define DIAG_OFF  (RMAX_OFF + NR)           // NR
#define ZERO_FLOATS (GMAX_OFF + 1)

#define DN 0.42044820762685725f             // 32^-0.25
#define RATIO 0.08838834764831845f          // 128^-0.5
#define EPSF 1e-4f

// ------- k1: fused features + dd + rowmax/diag + exp(dd-diag)*v accumulation
// Staging: each thread owns exactly ONE float4 per 16-row batch, address
// advances by a constant stride; LDS double-buffered so the load for batch
// s+1 is in flight during batch s's compute.
// NOTE: (256,4) empirically capped VGPR at 64 -> catastrophic spill (R5:
// 6.25GB scratch traffic). (256,2) -> cap 128, fits ~90 live regs, no spill.
__global__ __launch_bounds__(256, 2) void k_ctx1(const float* __restrict__ kk0,
                                                 const float* __restrict__ kk1,
                                                 const float* __restrict__ v0,
                                                 const float* __restrict__ v1,
                                                 const float* __restrict__ w,
                                                 float* __restrict__ ws) {
    __shared__ float sv[2][16][64];  // [0:32) feats*DN, [32:64) v packed per-c float4
    __shared__ float ddl[16][132];
    __shared__ float sdiag[16];
    __shared__ float bred[4];
    const int tid = threadIdx.x;
    const int m = tid & 127, half = tid >> 7;
    float wreg[DDIM];
    {
        const float4* w4 = (const float4*)(w + m*DDIM);
#pragma unroll
        for (int q = 0; q < 8; ++q) {
            const float4 t = w4[q];
            wreg[q*4+0]=t.x; wreg[q*4+1]=t.y; wreg[q*4+2]=t.z; wreg[q*4+3]=t.w;
        }
    }
    const int bh = blockIdx.x >> 5, chunk = blockIdx.x & 31;
    const int b = bh >> 3, h = bh & 7;
    const int nb0_0 = b*LL + chunk*256;
    // ---- per-thread staging descriptor (constant across batches) ----
    const float* gptr;
    int gstep, lds_lr, lo0, lo1, lo2, lo3;
    bool isfeat;
    if (tid < 32) {                    // k0 feats: 32 float4
        const int lr = tid >> 1, q = tid & 1;
        gptr = kk0 + (size_t)(nb0_0 + lr)*64 + h*8 + q*4;
        gstep = 16*64; lds_lr = lr; lo0 = q*4; lo1 = lo2 = lo3 = 0; isfeat = true;
    } else if (tid < 128) {            // k1 feats: 96 float4
        const int j = tid - 32, lr = j/6, r6 = j - lr*6;
        gptr = kk1 + (size_t)(nb0_0 + lr)*192 + h*24 + r6*4;
        gstep = 16*192; lds_lr = lr; lo0 = 8 + r6*4; lo1 = lo2 = lo3 = 0; isfeat = true;
    } else if (tid < 160) {            // v0: 32 float4 -> strided LDS (jj=0 slots)
        const int j = tid - 128, lr = j >> 1, q = j & 1;
        gptr = v0 + (size_t)(nb0_0 + lr)*64 + h*8 + q*4;
        gstep = 16*64; lds_lr = lr;
        lo0 = 32 + (q*4+0)*4; lo1 = 32 + (q*4+1)*4;
        lo2 = 32 + (q*4+2)*4; lo3 = 32 + (q*4+3)*4; isfeat = false;
    } else {                           // v1: 96 float4 -> scattered (jj=1..3 slots)
        const int j = tid - 160, lr = j/6, r6 = j - lr*6;
        gptr = v1 + (size_t)(nb0_0 + lr)*192 + h*24 + r6*4;
        gstep = 16*192; lds_lr = lr;
        const int e0 = r6*4;
        lo0 = 32 + ((e0+0)/3)*4 + 1 + (e0+0)%3;
        lo1 = 32 + ((e0+1)/3)*4 + 1 + (e0+1)%3;
        lo2 = 32 + ((e0+2)/3)*4 + 1 + (e0+2)%3;
        lo3 = 32 + ((e0+3)/3)*4 + 1 + (e0+3)%3; isfeat = false;
    }
    // ---- prologue: stage batch 0 into sv[0] ----
    {
        float4 val = *(const float4*)gptr; gptr += gstep;
        if (isfeat) {
            val.x *= DN; val.y *= DN; val.z *= DN; val.w *= DN;
            *(float4*)&sv[0][lds_lr][lo0] = val;
        } else {
            sv[0][lds_lr][lo0] = val.x; sv[0][lds_lr][lo1] = val.y;
            sv[0][lds_lr][lo2] = val.z; sv[0][lds_lr][lo3] = val.w;
        }
    }
    float acc[16];
#pragma unroll
    for (int i = 0; i < 16; ++i) acc[i] = 0.f;
    float ksum_acc = 0.f, vsum_acc = 0.f;
    float blockmax = -3.4e38f;
    float* rmaxg = ws + RMAX_OFF;
    float* diagg = ws + DIAG_OFF;
    __syncthreads();
    int cur = 0;
    for (int s = 0; s < 16; ++s) {
        const int nb0 = nb0_0 + s*16;
        // prefetch batch s+1 (latency hides under this batch's compute)
        float4 nval;
        if (s < 15) { nval = *(const float4*)gptr; gptr += gstep; }
        // diag: 16 lanes per row, shuffle reduce
        {
            const int row = tid >> 4, t16 = tid & 15;
            const float a = sv[cur][row][2*t16], b2 = sv[cur][row][2*t16+1];
            float ss = a*a + b2*b2;
            ss += __shfl_xor(ss, 1); ss += __shfl_xor(ss, 2);
            ss += __shfl_xor(ss, 4); ss += __shfl_xor(ss, 8);
            if (t16 == 0) { sdiag[row] = 0.5f*ss; diagg[(nb0+row)*8 + h] = 0.5f*ss; }
        }
        // dd for this half's 8 rows -> ddl
#pragma unroll
        for (int r8 = 0; r8 < 8; ++r8) {
            const int row = half*8 + r8;
            const float4* f4 = (const float4*)&sv[cur][row][0];
            float dd = 0.f;
#pragma unroll
            for (int q = 0; q < 8; ++q) {
                const float4 qv = f4[q];
                dd = fmaf(qv.x, wreg[q*4+0], dd);
                dd = fmaf(qv.y, wreg[q*4+1], dd);
                dd = fmaf(qv.z, wreg[q*4+2], dd);
                dd = fmaf(qv.w, wreg[q*4+3], dd);
            }
            ddl[row][m] = dd;
        }
        __syncthreads();
        // accumulate: EVERY thread, ALL 16 rows
#pragma unroll
        for (int row = 0; row < 16; ++row) {
            const float kp = __expf(ddl[row][m] - sdiag[row]);
            ksum_acc += kp;
            const float4* vv = (const float4*)&sv[cur][row][32];
#pragma unroll
            for (int cc = 0; cc < 4; ++cc) {
                const float4 vq = vv[half*4 + cc];
                acc[cc*4+0] = fmaf(kp, vq.x, acc[cc*4+0]);
                acc[cc*4+1] = fmaf(kp, vq.y, acc[cc*4+1]);
                acc[cc*4+2] = fmaf(kp, vq.z, acc[cc*4+2]);
                acc[cc*4+3] = fmaf(kp, vq.w, acc[cc*4+3]);
            }
        }
        if (tid < 32) {
#pragma unroll
            for (int lr = 0; lr < 16; ++lr) vsum_acc += sv[cur][lr][32 + tid];
        }
        // rowmax over m
        if (tid < 128) {
            const int row = tid >> 3, mo = tid & 7;
            float mx = -3.4e38f;
#pragma unroll
            for (int q = 0; q < 4; ++q) {
                const float4 v4 = *(const float4*)&ddl[row][mo*16 + q*4];
                mx = fmaxf(mx, fmaxf(fmaxf(v4.x, v4.y), fmaxf(v4.z, v4.w)));
            }
            mx = fmaxf(mx, __shfl_xor(mx, 1));
            mx = fmaxf(mx, __shfl_xor(mx, 2));
            mx = fmaxf(mx, __shfl_xor(mx, 4));
            if (mo == 0) rmaxg[(nb0+row)*8 + h] = mx;
            blockmax = fmaxf(blockmax, mx);
        }
        // write prefetched batch to the other buffer
        if (s < 15) {
            const int nxt = cur ^ 1;
            if (isfeat) {
                nval.x *= DN; nval.y *= DN; nval.z *= DN; nval.w *= DN;
                *(float4*)&sv[nxt][lds_lr][lo0] = nval;
            } else {
                sv[nxt][lds_lr][lo0] = nval.x; sv[nxt][lds_lr][lo1] = nval.y;
                sv[nxt][lds_lr][lo2] = nval.z; sv[nxt][lds_lr][lo3] = nval.w;
            }
        }
        __syncthreads();
        cur ^= 1;
    }
    float* ctxr = ws + CTXR_OFF;
#pragma unroll
    for (int cc = 0; cc < 4; ++cc) {
        const int c = half*4 + cc;
#pragma unroll
        for (int j = 0; j < 4; ++j)
            atomicAdd(&ctxr[((bh*8 + c)*MM + m)*4 + j], acc[cc*4+j]);
    }
    if (half == 0) atomicAdd(ws + KSUMR_OFF + bh*MM + m, ksum_acc);
    if (tid < 32)  atomicAdd(ws + VSUM_OFF + bh*32 + tid, vsum_acc);
    float bm = blockmax;
#pragma unroll
    for (int off = 32; off; off >>= 1) bm = fmaxf(bm, __shfl_xor(bm, off, 64));
    if ((tid & 63) == 0) bred[tid >> 6] = bm;
    __syncthreads();
    if (tid == 0) {
        const float g = fmaxf(fmaxf(bred[0], bred[1]), fmaxf(bred[2], bred[3]));
        unsigned u = __float_as_uint(g);
        u = (u & 0x80000000u) ? ~u : (u | 0x80000000u);
        atomicMax((unsigned*)(ws + GMAX_OFF), u);
    }
}

// ------- k3: finalize ctx/ksum, Qp from fresh k-gather, D_inv, readout -----
__global__ __launch_bounds__(256) void k_out(const float* __restrict__ kk0,
                                             const float* __restrict__ kk1,
                                             const float* __restrict__ w,
                                             const float* __restrict__ ws,
                                             float* __restrict__ out) {
    __shared__ float ctx_s[8*516];
    __shared__ float qpT[128*68];     // [m][row<64], pad 68 (b128-aligned)
    __shared__ float sf[64][36];      // feats*DN, pad 36 keeps float4 alignment
    __shared__ float sdiag[64], srmax[64], dinv[64], ksl[128];
    const int tid = threadIdx.x;
    const int m = tid & 127, half = tid >> 7;
    float wreg[DDIM];
    {
        const float4* w4 = (const float4*)(w + m*DDIM);
#pragma unroll
        for (int q = 0; q < 8; ++q) {
            const float4 t = w4[q];
            wreg[q*4+0]=t.x; wreg[q*4+1]=t.y; wreg[q*4+2]=t.z; wreg[q*4+3]=t.w;
        }
    }
    const int bh = blockIdx.x >> 6, blk = blockIdx.x & 63;
    const int b = bh >> 3, h = bh & 7;
    const unsigned gu = *((const unsigned*)(ws + GMAX_OFF));
    const float gm = (gu & 0x80000000u) ? __uint_as_float(gu & 0x7fffffffu)
                                        : __uint_as_float(~gu);
    const float alpha = __expf(-gm);
    const float* ctxr = ws + CTXR_OFF + bh*4096;
    const float* vsg  = ws + VSUM_OFF + bh*32;
    for (int g = tid; g < 4096; g += 256) {
        const int c = g >> 9, mm2 = (g >> 2) & 127, j = g & 3;
        ctx_s[c*516 + mm2*4 + j] = RATIO*(alpha*ctxr[g] + EPSF*vsg[c*4 + j]);
    }
    if (tid < 128) ksl[tid] = RATIO*(alpha*ws[KSUMR_OFF + bh*MM + tid] + EPSF*(float)LL);
    const float* rmaxg = ws + RMAX_OFF;
    const float* diagg = ws + DIAG_OFF;
    for (int tile = 0; tile < 2; ++tile) {
        const int lbase = blk*128 + tile*64;
        const int n0 = b*LL + lbase;
        __syncthreads();
        // stage 64 feature rows + diag/rmax
#pragma unroll
        for (int p = 0; p < 8; ++p) {
            const int i = tid + p*256;
            if (i < 512)       { const int lr = i >> 3, d = i & 7;
                                 sf[lr][d] = kk0[(n0+lr)*64 + h*8 + d] * DN; }
            else if (i < 2048) { const int jn = i - 512; const int lr = jn/24;
                                 const int d2 = jn - lr*24;
                                 sf[lr][8 + d2] = kk1[(n0+lr)*192 + h*24 + d2] * DN; }
        }
        if (tid < 64)       sdiag[tid]    = diagg[(n0+tid)*8 + h];
        else if (tid < 128) srmax[tid-64] = rmaxg[(n0+tid-64)*8 + h];
        __syncthreads();
        // phase A: Qp for 64 rows -> qpT
#pragma unroll
        for (int r4 = 0; r4 < 8; ++r4) {
            float q4[4];
#pragma unroll
            for (int k = 0; k < 4; ++k) {
                const int row = half*32 + r4*4 + k;
                const float4* f4 = (const float4*)&sf[row][0];
                float dd = 0.f;
#pragma unroll
                for (int q = 0; q < 8; ++q) {
                    const float4 qv = f4[q];
                    dd = fmaf(qv.x, wreg[q*4+0], dd);
                    dd = fmaf(qv.y, wreg[q*4+1], dd);
                    dd = fmaf(qv.z, wreg[q*4+2], dd);
                    dd = fmaf(qv.w, wreg[q*4+3], dd);
                }
                q4[k] = RATIO*(__expf(dd - sdiag[row] - srmax[row]) + EPSF);
            }
            *(float4*)&qpT[m*68 + half*32 + r4*4] = make_float4(q4[0],q4[1],q4[2],q4[3]);
        }
        __syncthreads();
        // phase B: D_inv
        {
            const int row = tid >> 2, mq = tid & 3;
            float ssum = 0.f;
#pragma unroll
            for (int i = 0; i < 32; ++i) {
                const int mm2 = mq*32 + i;
                ssum = fmaf(qpT[mm2*68 + row], ksl[mm2], ssum);
            }
            ssum += __shfl_xor(ssum, 1);
            ssum += __shfl_xor(ssum, 2);
            if (mq == 0) dinv[row] = 1.f/ssum;
        }
        __syncthreads();
        // phase C: out = (qp . ctx) * dinv, register-tiled
        {
            const int c = tid & 7, mh = (tid >> 3) & 1, rg = tid >> 4;
            float4 a0 = {0,0,0,0}, a1 = {0,0,0,0}, a2 = {0,0,0,0}, a3 = {0,0,0,0};
            const float4* cx = (const float4*)&ctx_s[c*516];
            const int mstart = mh*64;
#pragma unroll 8
            for (int i = 0; i < 64; ++i) {
                const int mm2 = mstart + i;
                const float4 cv = cx[mm2];
                const float4 qv = *(const float4*)&qpT[mm2*68 + rg*4];
                a0.x = fmaf(qv.x, cv.x, a0.x); a0.y = fmaf(qv.x, cv.y, a0.y);
                a0.z = fmaf(qv.x, cv.z, a0.z); a0.w = fmaf(qv.x, cv.w, a0.w);
                a1.x = fmaf(qv.y, cv.x, a1.x); a1.y = fmaf(qv.y, cv.y, a1.y);
                a1.z = fmaf(qv.y, cv.z, a1.z); a1.w = fmaf(qv.y, cv.w, a1.w);
                a2.x = fmaf(qv.z, cv.x, a2.x); a2.y = fmaf(qv.z, cv.y, a2.y);
                a2.z = fmaf(qv.z, cv.z, a2.z); a2.w = fmaf(qv.z, cv.w, a2.w);
                a3.x = fmaf(qv.w, cv.x, a3.x); a3.y = fmaf(qv.w, cv.y, a3.y);
                a3.z = fmaf(qv.w, cv.z, a3.z); a3.w = fmaf(qv.w, cv.w, a3.w);
            }
            a0.x += __shfl_xor(a0.x, 8); a0.y += __shfl_xor(a0.y, 8);
            a0.z += __shfl_xor(a0.z, 8); a0.w += __shfl_xor(a0.w, 8);
            a1.x += __shfl_xor(a1.x, 8); a1.y += __shfl_xor(a1.y, 8);
            a1.z += __shfl_xor(a1.z, 8); a1.w += __shfl_xor(a1.w, 8);
            a2.x += __shfl_xor(a2.x, 8); a2.y += __shfl_xor(a2.y, 8);
            a2.z += __shfl_xor(a2.z, 8); a2.w += __shfl_xor(a2.w, 8);
            a3.x += __shfl_xor(a3.x, 8); a3.y += __shfl_xor(a3.y, 8);
            a3.z += __shfl_xor(a3.z, 8); a3.w += __shfl_xor(a3.w, 8);
            const float4 s0 = mh ? a2 : a0;
            const float4 s1 = mh ? a3 : a1;
            const int lr0 = rg*4 + mh*2;
#pragma unroll
            for (int k = 0; k < 2; ++k) {
                const float4 sv4 = k ? s1 : s0;
                const int lr = lr0 + k;
                const float dv = dinv[lr];
                const int n = n0 + lr;
                const int base = n*64 + h*8 + c;
                out[base] = sv4.x * dv;
                float* o1 = out + NN*64 + base*3;
                o1[0] = sv4.y * dv;
                o1[1] = sv4.z * dv;
                o1[2] = sv4.w * dv;
            }
        }
    }
}

extern "C" void kernel_launch(void* const* d_in, const int* in_sizes, int n_in,
                              void* d_out, int out_size, void* d_ws, size_t ws_size,
                              hipStream_t stream) {
    const float* v0 = (const float*)d_in[0];
    const float* v1 = (const float*)d_in[1];
    const float* k0 = (const float*)d_in[2];
    const float* k1 = (const float*)d_in[3];
    const float* w  = (const float*)d_in[6];
    float* out = (float*)d_out;
    float* ws  = (float*)d_ws;
    hipMemsetAsync(ws, 0, (size_t)ZERO_FLOATS*sizeof(float), stream);
    k_ctx1<<<1024, 256, 0, stream>>>(k0, k1, v0, v1, w, ws);
    k_out <<<2048, 256, 0, stream>>>(k0, k1, w, ws, out);
}

// Round 7
// 340.132 us; speedup vs baseline: 5.5017x; 2.3000x over previous
//
#include <hip/hip_runtime.h>

#define BB 4
#define HH 8
#define LL 8192
#define NN (BB*LL)
#define DDIM 32
#define MM 128
#define NR (NN*HH)          // 262144 (n,h) rows

// ws layout (float offsets)
#define CTXR_OFF 0                          // 32*8*128*4 = 131072
#define KSUMR_OFF (CTXR_OFF + 32*8*MM*4)    // 4096
#define VSUM_OFF  (KSUMR_OFF + 32*MM)       // 1024
#define GMAX_OFF  (VSUM_OFF + 32*32)        // 1
#define RMAX_OFF  (GMAX_OFF + 1)            // NR
#define DIAG_OFF  (RMAX_OFF + NR)           // NR
#define ZERO_FLOATS (GMAX_OFF + 1)

#define DN 0.42044820762685725f             // 32^-0.25
#define RATIO 0.08838834764831845f          // 128^-0.5
#define EPSF 1e-4f

// ------- k1: fused features + dd + rowmax/diag + exp(dd-diag)*v accumulation
// (256,2): VGPR cap 128 (R5's (256,4) capped at 64 -> 6GB spill).
// Row loops unroll-limited: full unroll let the scheduler batch ~80 LDS
// reads -> live set >128 -> spill (R6: 2GB scratch writes). unroll 2/4
// keeps the window ~95 regs.
__global__ __launch_bounds__(256, 2) void k_ctx1(const float* __restrict__ kk0,
                                                 const float* __restrict__ kk1,
                                                 const float* __restrict__ v0,
                                                 const float* __restrict__ v1,
                                                 const float* __restrict__ w,
                                                 float* __restrict__ ws) {
    __shared__ float sv[2][16][64];  // [0:32) feats*DN, [32:64) v packed per-c float4
    __shared__ float ddl[16][132];
    __shared__ float sdiag[16];
    __shared__ float bred[4];
    const int tid = threadIdx.x;
    const int m = tid & 127, half = tid >> 7;
    float wreg[DDIM];
    {
        const float4* w4 = (const float4*)(w + m*DDIM);
#pragma unroll
        for (int q = 0; q < 8; ++q) {
            const float4 t = w4[q];
            wreg[q*4+0]=t.x; wreg[q*4+1]=t.y; wreg[q*4+2]=t.z; wreg[q*4+3]=t.w;
        }
    }
    const int bh = blockIdx.x >> 5, chunk = blockIdx.x & 31;
    const int b = bh >> 3, h = bh & 7;
    const int nb0_0 = b*LL + chunk*256;
    // ---- per-thread staging descriptor (constant across batches) ----
    const float* gptr;
    int gstep, lds_lr, lo0, lo1, lo2, lo3;
    bool isfeat;
    if (tid < 32) {                    // k0 feats: 32 float4
        const int lr = tid >> 1, q = tid & 1;
        gptr = kk0 + (size_t)(nb0_0 + lr)*64 + h*8 + q*4;
        gstep = 16*64; lds_lr = lr; lo0 = q*4; lo1 = lo2 = lo3 = 0; isfeat = true;
    } else if (tid < 128) {            // k1 feats: 96 float4
        const int j = tid - 32, lr = j/6, r6 = j - lr*6;
        gptr = kk1 + (size_t)(nb0_0 + lr)*192 + h*24 + r6*4;
        gstep = 16*192; lds_lr = lr; lo0 = 8 + r6*4; lo1 = lo2 = lo3 = 0; isfeat = true;
    } else if (tid < 160) {            // v0: 32 float4 -> strided LDS (jj=0 slots)
        const int j = tid - 128, lr = j >> 1, q = j & 1;
        gptr = v0 + (size_t)(nb0_0 + lr)*64 + h*8 + q*4;
        gstep = 16*64; lds_lr = lr;
        lo0 = 32 + (q*4+0)*4; lo1 = 32 + (q*4+1)*4;
        lo2 = 32 + (q*4+2)*4; lo3 = 32 + (q*4+3)*4; isfeat = false;
    } else {                           // v1: 96 float4 -> scattered (jj=1..3 slots)
        const int j = tid - 160, lr = j/6, r6 = j - lr*6;
        gptr = v1 + (size_t)(nb0_0 + lr)*192 + h*24 + r6*4;
        gstep = 16*192; lds_lr = lr;
        const int e0 = r6*4;
        lo0 = 32 + ((e0+0)/3)*4 + 1 + (e0+0)%3;
        lo1 = 32 + ((e0+1)/3)*4 + 1 + (e0+1)%3;
        lo2 = 32 + ((e0+2)/3)*4 + 1 + (e0+2)%3;
        lo3 = 32 + ((e0+3)/3)*4 + 1 + (e0+3)%3; isfeat = false;
    }
    // ---- prologue: stage batch 0 into sv[0] ----
    {
        float4 val = *(const float4*)gptr; gptr += gstep;
        if (isfeat) {
            val.x *= DN; val.y *= DN; val.z *= DN; val.w *= DN;
            *(float4*)&sv[0][lds_lr][lo0] = val;
        } else {
            sv[0][lds_lr][lo0] = val.x; sv[0][lds_lr][lo1] = val.y;
            sv[0][lds_lr][lo2] = val.z; sv[0][lds_lr][lo3] = val.w;
        }
    }
    float acc[16];
#pragma unroll
    for (int i = 0; i < 16; ++i) acc[i] = 0.f;
    float ksum_acc = 0.f, vsum_acc = 0.f;
    float blockmax = -3.4e38f;
    float* rmaxg = ws + RMAX_OFF;
    float* diagg = ws + DIAG_OFF;
    __syncthreads();
    int cur = 0;
    for (int s = 0; s < 16; ++s) {
        const int nb0 = nb0_0 + s*16;
        // prefetch batch s+1 (latency hides under this batch's compute)
        float4 nval;
        if (s < 15) { nval = *(const float4*)gptr; gptr += gstep; }
        // diag: 16 lanes per row, shuffle reduce
        {
            const int row = tid >> 4, t16 = tid & 15;
            const float a = sv[cur][row][2*t16], b2 = sv[cur][row][2*t16+1];
            float ss = a*a + b2*b2;
            ss += __shfl_xor(ss, 1); ss += __shfl_xor(ss, 2);
            ss += __shfl_xor(ss, 4); ss += __shfl_xor(ss, 8);
            if (t16 == 0) { sdiag[row] = 0.5f*ss; diagg[(nb0+row)*8 + h] = 0.5f*ss; }
        }
        // dd for this half's 8 rows -> ddl (unroll-limited: reg window)
#pragma unroll 2
        for (int r8 = 0; r8 < 8; ++r8) {
            const int row = half*8 + r8;
            const float4* f4 = (const float4*)&sv[cur][row][0];
            float dd = 0.f;
#pragma unroll
            for (int q = 0; q < 8; ++q) {
                const float4 qv = f4[q];
                dd = fmaf(qv.x, wreg[q*4+0], dd);
                dd = fmaf(qv.y, wreg[q*4+1], dd);
                dd = fmaf(qv.z, wreg[q*4+2], dd);
                dd = fmaf(qv.w, wreg[q*4+3], dd);
            }
            ddl[row][m] = dd;
        }
        __syncthreads();
        // accumulate: EVERY thread, ALL 16 rows (unroll-limited: reg window)
#pragma unroll 4
        for (int row = 0; row < 16; ++row) {
            const float kp = __expf(ddl[row][m] - sdiag[row]);
            ksum_acc += kp;
            const float4* vv = (const float4*)&sv[cur][row][32];
#pragma unroll
            for (int cc = 0; cc < 4; ++cc) {
                const float4 vq = vv[half*4 + cc];
                acc[cc*4+0] = fmaf(kp, vq.x, acc[cc*4+0]);
                acc[cc*4+1] = fmaf(kp, vq.y, acc[cc*4+1]);
                acc[cc*4+2] = fmaf(kp, vq.z, acc[cc*4+2]);
                acc[cc*4+3] = fmaf(kp, vq.w, acc[cc*4+3]);
            }
        }
        if (tid < 32) {
#pragma unroll 4
            for (int lr = 0; lr < 16; ++lr) vsum_acc += sv[cur][lr][32 + tid];
        }
        // rowmax over m
        if (tid < 128) {
            const int row = tid >> 3, mo = tid & 7;
            float mx = -3.4e38f;
#pragma unroll
            for (int q = 0; q < 4; ++q) {
                const float4 v4 = *(const float4*)&ddl[row][mo*16 + q*4];
                mx = fmaxf(mx, fmaxf(fmaxf(v4.x, v4.y), fmaxf(v4.z, v4.w)));
            }
            mx = fmaxf(mx, __shfl_xor(mx, 1));
            mx = fmaxf(mx, __shfl_xor(mx, 2));
            mx = fmaxf(mx, __shfl_xor(mx, 4));
            if (mo == 0) rmaxg[(nb0+row)*8 + h] = mx;
            blockmax = fmaxf(blockmax, mx);
        }
        // write prefetched batch to the other buffer
        if (s < 15) {
            const int nxt = cur ^ 1;
            if (isfeat) {
                nval.x *= DN; nval.y *= DN; nval.z *= DN; nval.w *= DN;
                *(float4*)&sv[nxt][lds_lr][lo0] = nval;
            } else {
                sv[nxt][lds_lr][lo0] = nval.x; sv[nxt][lds_lr][lo1] = nval.y;
                sv[nxt][lds_lr][lo2] = nval.z; sv[nxt][lds_lr][lo3] = nval.w;
            }
        }
        __syncthreads();
        cur ^= 1;
    }
    float* ctxr = ws + CTXR_OFF;
#pragma unroll
    for (int cc = 0; cc < 4; ++cc) {
        const int c = half*4 + cc;
#pragma unroll
        for (int j = 0; j < 4; ++j)
            atomicAdd(&ctxr[((bh*8 + c)*MM + m)*4 + j], acc[cc*4+j]);
    }
    if (half == 0) atomicAdd(ws + KSUMR_OFF + bh*MM + m, ksum_acc);
    if (tid < 32)  atomicAdd(ws + VSUM_OFF + bh*32 + tid, vsum_acc);
    float bm = blockmax;
#pragma unroll
    for (int off = 32; off; off >>= 1) bm = fmaxf(bm, __shfl_xor(bm, off, 64));
    if ((tid & 63) == 0) bred[tid >> 6] = bm;
    __syncthreads();
    if (tid == 0) {
        const float g = fmaxf(fmaxf(bred[0], bred[1]), fmaxf(bred[2], bred[3]));
        unsigned u = __float_as_uint(g);
        u = (u & 0x80000000u) ? ~u : (u | 0x80000000u);
        atomicMax((unsigned*)(ws + GMAX_OFF), u);
    }
}

// ------- k3: finalize ctx/ksum, Qp from fresh k-gather, D_inv, readout -----
__global__ __launch_bounds__(256) void k_out(const float* __restrict__ kk0,
                                             const float* __restrict__ kk1,
                                             const float* __restrict__ w,
                                             const float* __restrict__ ws,
                                             float* __restrict__ out) {
    __shared__ float ctx_s[8*516];
    __shared__ float qpT[128*68];     // [m][row<64], pad 68 (b128-aligned)
    __shared__ float sf[64][36];      // feats*DN, pad 36 keeps float4 alignment
    __shared__ float sdiag[64], srmax[64], dinv[64], ksl[128];
    const int tid = threadIdx.x;
    const int m = tid & 127, half = tid >> 7;
    float wreg[DDIM];
    {
        const float4* w4 = (const float4*)(w + m*DDIM);
#pragma unroll
        for (int q = 0; q < 8; ++q) {
            const float4 t = w4[q];
            wreg[q*4+0]=t.x; wreg[q*4+1]=t.y; wreg[q*4+2]=t.z; wreg[q*4+3]=t.w;
        }
    }
    const int bh = blockIdx.x >> 6, blk = blockIdx.x & 63;
    const int b = bh >> 3, h = bh & 7;
    const unsigned gu = *((const unsigned*)(ws + GMAX_OFF));
    const float gm = (gu & 0x80000000u) ? __uint_as_float(gu & 0x7fffffffu)
                                        : __uint_as_float(~gu);
    const float alpha = __expf(-gm);
    const float* ctxr = ws + CTXR_OFF + bh*4096;
    const float* vsg  = ws + VSUM_OFF + bh*32;
    for (int g = tid; g < 4096; g += 256) {
        const int c = g >> 9, mm2 = (g >> 2) & 127, j = g & 3;
        ctx_s[c*516 + mm2*4 + j] = RATIO*(alpha*ctxr[g] + EPSF*vsg[c*4 + j]);
    }
    if (tid < 128) ksl[tid] = RATIO*(alpha*ws[KSUMR_OFF + bh*MM + tid] + EPSF*(float)LL);
    const float* rmaxg = ws + RMAX_OFF;
    const float* diagg = ws + DIAG_OFF;
    for (int tile = 0; tile < 2; ++tile) {
        const int lbase = blk*128 + tile*64;
        const int n0 = b*LL + lbase;
        __syncthreads();
        // stage 64 feature rows + diag/rmax
#pragma unroll
        for (int p = 0; p < 8; ++p) {
            const int i = tid + p*256;
            if (i < 512)       { const int lr = i >> 3, d = i & 7;
                                 sf[lr][d] = kk0[(n0+lr)*64 + h*8 + d] * DN; }
            else if (i < 2048) { const int jn = i - 512; const int lr = jn/24;
                                 const int d2 = jn - lr*24;
                                 sf[lr][8 + d2] = kk1[(n0+lr)*192 + h*24 + d2] * DN; }
        }
        if (tid < 64)       sdiag[tid]    = diagg[(n0+tid)*8 + h];
        else if (tid < 128) srmax[tid-64] = rmaxg[(n0+tid-64)*8 + h];
        __syncthreads();
        // phase A: Qp for 64 rows -> qpT
#pragma unroll 2
        for (int r4 = 0; r4 < 8; ++r4) {
            float q4[4];
#pragma unroll
            for (int k = 0; k < 4; ++k) {
                const int row = half*32 + r4*4 + k;
                const float4* f4 = (const float4*)&sf[row][0];
                float dd = 0.f;
#pragma unroll
                for (int q = 0; q < 8; ++q) {
                    const float4 qv = f4[q];
                    dd = fmaf(qv.x, wreg[q*4+0], dd);
                    dd = fmaf(qv.y, wreg[q*4+1], dd);
                    dd = fmaf(qv.z, wreg[q*4+2], dd);
                    dd = fmaf(qv.w, wreg[q*4+3], dd);
                }
                q4[k] = RATIO*(__expf(dd - sdiag[row] - srmax[row]) + EPSF);
            }
            *(float4*)&qpT[m*68 + half*32 + r4*4] = make_float4(q4[0],q4[1],q4[2],q4[3]);
        }
        __syncthreads();
        // phase B: D_inv
        {
            const int row = tid >> 2, mq = tid & 3;
            float ssum = 0.f;
#pragma unroll
            for (int i = 0; i < 32; ++i) {
                const int mm2 = mq*32 + i;
                ssum = fmaf(qpT[mm2*68 + row], ksl[mm2], ssum);
            }
            ssum += __shfl_xor(ssum, 1);
            ssum += __shfl_xor(ssum, 2);
            if (mq == 0) dinv[row] = 1.f/ssum;
        }
        __syncthreads();
        // phase C: out = (qp . ctx) * dinv, register-tiled
        {
            const int c = tid & 7, mh = (tid >> 3) & 1, rg = tid >> 4;
            float4 a0 = {0,0,0,0}, a1 = {0,0,0,0}, a2 = {0,0,0,0}, a3 = {0,0,0,0};
            const float4* cx = (const float4*)&ctx_s[c*516];
            const int mstart = mh*64;
#pragma unroll 8
            for (int i = 0; i < 64; ++i) {
                const int mm2 = mstart + i;
                const float4 cv = cx[mm2];
                const float4 qv = *(const float4*)&qpT[mm2*68 + rg*4];
                a0.x = fmaf(qv.x, cv.x, a0.x); a0.y = fmaf(qv.x, cv.y, a0.y);
                a0.z = fmaf(qv.x, cv.z, a0.z); a0.w = fmaf(qv.x, cv.w, a0.w);
                a1.x = fmaf(qv.y, cv.x, a1.x); a1.y = fmaf(qv.y, cv.y, a1.y);
                a1.z = fmaf(qv.y, cv.z, a1.z); a1.w = fmaf(qv.y, cv.w, a1.w);
                a2.x = fmaf(qv.z, cv.x, a2.x); a2.y = fmaf(qv.z, cv.y, a2.y);
                a2.z = fmaf(qv.z, cv.z, a2.z); a2.w = fmaf(qv.z, cv.w, a2.w);
                a3.x = fmaf(qv.w, cv.x, a3.x); a3.y = fmaf(qv.w, cv.y, a3.y);
                a3.z = fmaf(qv.w, cv.z, a3.z); a3.w = fmaf(qv.w, cv.w, a3.w);
            }
            a0.x += __shfl_xor(a0.x, 8); a0.y += __shfl_xor(a0.y, 8);
            a0.z += __shfl_xor(a0.z, 8); a0.w += __shfl_xor(a0.w, 8);
            a1.x += __shfl_xor(a1.x, 8); a1.y += __shfl_xor(a1.y, 8);
            a1.z += __shfl_xor(a1.z, 8); a1.w += __shfl_xor(a1.w, 8);
            a2.x += __shfl_xor(a2.x, 8); a2.y += __shfl_xor(a2.y, 8);
            a2.z += __shfl_xor(a2.z, 8); a2.w += __shfl_xor(a2.w, 8);
            a3.x += __shfl_xor(a3.x, 8); a3.y += __shfl_xor(a3.y, 8);
            a3.z += __shfl_xor(a3.z, 8); a3.w += __shfl_xor(a3.w, 8);
            const float4 s0 = mh ? a2 : a0;
            const float4 s1 = mh ? a3 : a1;
            const int lr0 = rg*4 + mh*2;
#pragma unroll
            for (int k = 0; k < 2; ++k) {
                const float4 sv4 = k ? s1 : s0;
                const int lr = lr0 + k;
                const float dv = dinv[lr];
                const int n = n0 + lr;
                const int base = n*64 + h*8 + c;
                out[base] = sv4.x * dv;
                float* o1 = out + NN*64 + base*3;
                o1[0] = sv4.y * dv;
                o1[1] = sv4.z * dv;
                o1[2] = sv4.w * dv;
            }
        }
    }
}

extern "C" void kernel_launch(void* const* d_in, const int* in_sizes, int n_in,
                              void* d_out, int out_size, void* d_ws, size_t ws_size,
                              hipStream_t stream) {
    const float* v0 = (const float*)d_in[0];
    const float* v1 = (const float*)d_in[1];
    const float* k0 = (const float*)d_in[2];
    const float* k1 = (const float*)d_in[3];
    const float* w  = (const float*)d_in[6];
    float* out = (float*)d_out;
    float* ws  = (float*)d_ws;
    hipMemsetAsync(ws, 0, (size_t)ZERO_FLOATS*sizeof(float), stream);
    k_ctx1<<<1024, 256, 0, stream>>>(k0, k1, v0, v1, w, ws);
    k_out <<<2048, 256, 0, stream>>>(k0, k1, w, ws, out);
}

// Round 8
// 322.350 us; speedup vs baseline: 5.8052x; 1.0552x over previous
//
#include <hip/hip_runtime.h>

#define BB 4
#define HH 8
#define LL 8192
#define NN (BB*LL)
#define DDIM 32
#define MM 128
#define NR (NN*HH)          // 262144 (n,h) rows

// ws layout (float offsets)
#define CTXR_OFF 0                          // 32*8*128*4 = 131072
#define KSUMR_OFF (CTXR_OFF + 32*8*MM*4)    // 4096
#define VSUM_OFF  (KSUMR_OFF + 32*MM)       // 1024
#define GMAX_OFF  (VSUM_OFF + 32*32)        // 1
#define RMAX_OFF  (GMAX_OFF + 1)            // NR
#define DIAG_OFF  (RMAX_OFF + NR)           // NR
#define ZERO_FLOATS (GMAX_OFF + 1)

#define DN 0.42044820762685725f             // 32^-0.25
#define RATIO 0.08838834764831845f          // 128^-0.5
#define EPSF 1e-4f

// ------- k1: fused features + dd + rowmax/diag + exp(dd-diag)*v accumulation
// (256,2): VGPR cap 128 (R5's (256,4) capped at 64 -> 6GB spill).
// Row loops unroll-limited (R6: full unroll batched ~80 LDS reads -> spill).
// R8: grid 2048 (was 1024) -- VGPR=80 allows 6 waves/SIMD, LDS allows 9
// blocks/CU; the grid was the occupancy limiter (R7: 25% occ, VALU 34%).
__global__ __launch_bounds__(256, 2) void k_ctx1(const float* __restrict__ kk0,
                                                 const float* __restrict__ kk1,
                                                 const float* __restrict__ v0,
                                                 const float* __restrict__ v1,
                                                 const float* __restrict__ w,
                                                 float* __restrict__ ws) {
    __shared__ float sv[2][16][64];  // [0:32) feats*DN, [32:64) v packed per-c float4
    __shared__ float ddl[16][132];
    __shared__ float sdiag[16];
    __shared__ float bred[4];
    const int tid = threadIdx.x;
    const int m = tid & 127, half = tid >> 7;
    float wreg[DDIM];
    {
        const float4* w4 = (const float4*)(w + m*DDIM);
#pragma unroll
        for (int q = 0; q < 8; ++q) {
            const float4 t = w4[q];
            wreg[q*4+0]=t.x; wreg[q*4+1]=t.y; wreg[q*4+2]=t.z; wreg[q*4+3]=t.w;
        }
    }
    const int bh = blockIdx.x >> 6, chunk = blockIdx.x & 63;   // 64 chunks x 128 rows
    const int b = bh >> 3, h = bh & 7;
    const int nb0_0 = b*LL + chunk*128;
    // ---- per-thread staging descriptor (constant across batches) ----
    const float* gptr;
    int gstep, lds_lr, lo0, lo1, lo2, lo3;
    bool isfeat;
    if (tid < 32) {                    // k0 feats: 32 float4
        const int lr = tid >> 1, q = tid & 1;
        gptr = kk0 + (size_t)(nb0_0 + lr)*64 + h*8 + q*4;
        gstep = 16*64; lds_lr = lr; lo0 = q*4; lo1 = lo2 = lo3 = 0; isfeat = true;
    } else if (tid < 128) {            // k1 feats: 96 float4
        const int j = tid - 32, lr = j/6, r6 = j - lr*6;
        gptr = kk1 + (size_t)(nb0_0 + lr)*192 + h*24 + r6*4;
        gstep = 16*192; lds_lr = lr; lo0 = 8 + r6*4; lo1 = lo2 = lo3 = 0; isfeat = true;
    } else if (tid < 160) {            // v0: 32 float4 -> strided LDS (jj=0 slots)
        const int j = tid - 128, lr = j >> 1, q = j & 1;
        gptr = v0 + (size_t)(nb0_0 + lr)*64 + h*8 + q*4;
        gstep = 16*64; lds_lr = lr;
        lo0 = 32 + (q*4+0)*4; lo1 = 32 + (q*4+1)*4;
        lo2 = 32 + (q*4+2)*4; lo3 = 32 + (q*4+3)*4; isfeat = false;
    } else {                           // v1: 96 float4 -> scattered (jj=1..3 slots)
        const int j = tid - 160, lr = j/6, r6 = j - lr*6;
        gptr = v1 + (size_t)(nb0_0 + lr)*192 + h*24 + r6*4;
        gstep = 16*192; lds_lr = lr;
        const int e0 = r6*4;
        lo0 = 32 + ((e0+0)/3)*4 + 1 + (e0+0)%3;
        lo1 = 32 + ((e0+1)/3)*4 + 1 + (e0+1)%3;
        lo2 = 32 + ((e0+2)/3)*4 + 1 + (e0+2)%3;
        lo3 = 32 + ((e0+3)/3)*4 + 1 + (e0+3)%3; isfeat = false;
    }
    // ---- prologue: stage batch 0 into sv[0] ----
    {
        float4 val = *(const float4*)gptr; gptr += gstep;
        if (isfeat) {
            val.x *= DN; val.y *= DN; val.z *= DN; val.w *= DN;
            *(float4*)&sv[0][lds_lr][lo0] = val;
        } else {
            sv[0][lds_lr][lo0] = val.x; sv[0][lds_lr][lo1] = val.y;
            sv[0][lds_lr][lo2] = val.z; sv[0][lds_lr][lo3] = val.w;
        }
    }
    float acc[16];
#pragma unroll
    for (int i = 0; i < 16; ++i) acc[i] = 0.f;
    float ksum_acc = 0.f, vsum_acc = 0.f;
    float blockmax = -3.4e38f;
    float* rmaxg = ws + RMAX_OFF;
    float* diagg = ws + DIAG_OFF;
    __syncthreads();
    int cur = 0;
    for (int s = 0; s < 8; ++s) {
        const int nb0 = nb0_0 + s*16;
        // prefetch batch s+1 (latency hides under this batch's compute)
        float4 nval;
        if (s < 7) { nval = *(const float4*)gptr; gptr += gstep; }
        // diag: 16 lanes per row, shuffle reduce
        {
            const int row = tid >> 4, t16 = tid & 15;
            const float a = sv[cur][row][2*t16], b2 = sv[cur][row][2*t16+1];
            float ss = a*a + b2*b2;
            ss += __shfl_xor(ss, 1); ss += __shfl_xor(ss, 2);
            ss += __shfl_xor(ss, 4); ss += __shfl_xor(ss, 8);
            if (t16 == 0) { sdiag[row] = 0.5f*ss; diagg[(nb0+row)*8 + h] = 0.5f*ss; }
        }
        // dd for this half's 8 rows -> ddl (unroll-limited: reg window)
#pragma unroll 2
        for (int r8 = 0; r8 < 8; ++r8) {
            const int row = half*8 + r8;
            const float4* f4 = (const float4*)&sv[cur][row][0];
            float dd = 0.f;
#pragma unroll
            for (int q = 0; q < 8; ++q) {
                const float4 qv = f4[q];
                dd = fmaf(qv.x, wreg[q*4+0], dd);
                dd = fmaf(qv.y, wreg[q*4+1], dd);
                dd = fmaf(qv.z, wreg[q*4+2], dd);
                dd = fmaf(qv.w, wreg[q*4+3], dd);
            }
            ddl[row][m] = dd;
        }
        __syncthreads();
        // accumulate: EVERY thread, ALL 16 rows (unroll-limited: reg window)
#pragma unroll 4
        for (int row = 0; row < 16; ++row) {
            const float kp = __expf(ddl[row][m] - sdiag[row]);
            ksum_acc += kp;
            const float4* vv = (const float4*)&sv[cur][row][32];
#pragma unroll
            for (int cc = 0; cc < 4; ++cc) {
                const float4 vq = vv[half*4 + cc];
                acc[cc*4+0] = fmaf(kp, vq.x, acc[cc*4+0]);
                acc[cc*4+1] = fmaf(kp, vq.y, acc[cc*4+1]);
                acc[cc*4+2] = fmaf(kp, vq.z, acc[cc*4+2]);
                acc[cc*4+3] = fmaf(kp, vq.w, acc[cc*4+3]);
            }
        }
        if (tid < 32) {
#pragma unroll 4
            for (int lr = 0; lr < 16; ++lr) vsum_acc += sv[cur][lr][32 + tid];
        }
        // rowmax over m
        if (tid < 128) {
            const int row = tid >> 3, mo = tid & 7;
            float mx = -3.4e38f;
#pragma unroll
            for (int q = 0; q < 4; ++q) {
                const float4 v4 = *(const float4*)&ddl[row][mo*16 + q*4];
                mx = fmaxf(mx, fmaxf(fmaxf(v4.x, v4.y), fmaxf(v4.z, v4.w)));
            }
            mx = fmaxf(mx, __shfl_xor(mx, 1));
            mx = fmaxf(mx, __shfl_xor(mx, 2));
            mx = fmaxf(mx, __shfl_xor(mx, 4));
            if (mo == 0) rmaxg[(nb0+row)*8 + h] = mx;
            blockmax = fmaxf(blockmax, mx);
        }
        // write prefetched batch to the other buffer
        if (s < 7) {
            const int nxt = cur ^ 1;
            if (isfeat) {
                nval.x *= DN; nval.y *= DN; nval.z *= DN; nval.w *= DN;
                *(float4*)&sv[nxt][lds_lr][lo0] = nval;
            } else {
                sv[nxt][lds_lr][lo0] = nval.x; sv[nxt][lds_lr][lo1] = nval.y;
                sv[nxt][lds_lr][lo2] = nval.z; sv[nxt][lds_lr][lo3] = nval.w;
            }
        }
        __syncthreads();
        cur ^= 1;
    }
    float* ctxr = ws + CTXR_OFF;
#pragma unroll
    for (int cc = 0; cc < 4; ++cc) {
        const int c = half*4 + cc;
#pragma unroll
        for (int j = 0; j < 4; ++j)
            atomicAdd(&ctxr[((bh*8 + c)*MM + m)*4 + j], acc[cc*4+j]);
    }
    if (half == 0) atomicAdd(ws + KSUMR_OFF + bh*MM + m, ksum_acc);
    if (tid < 32)  atomicAdd(ws + VSUM_OFF + bh*32 + tid, vsum_acc);
    float bm = blockmax;
#pragma unroll
    for (int off = 32; off; off >>= 1) bm = fmaxf(bm, __shfl_xor(bm, off, 64));
    if ((tid & 63) == 0) bred[tid >> 6] = bm;
    __syncthreads();
    if (tid == 0) {
        const float g = fmaxf(fmaxf(bred[0], bred[1]), fmaxf(bred[2], bred[3]));
        unsigned u = __float_as_uint(g);
        u = (u & 0x80000000u) ? ~u : (u | 0x80000000u);
        atomicMax((unsigned*)(ws + GMAX_OFF), u);
    }
}

// ------- k3: finalize ctx/ksum, Qp from fresh k-gather, D_inv, readout -----
__global__ __launch_bounds__(256) void k_out(const float* __restrict__ kk0,
                                             const float* __restrict__ kk1,
                                             const float* __restrict__ w,
                                             const float* __restrict__ ws,
                                             float* __restrict__ out) {
    __shared__ float ctx_s[8*516];
    __shared__ float qpT[128*68];     // [m][row<64], pad 68 (b128-aligned)
    __shared__ float sf[64][36];      // feats*DN, pad 36 keeps float4 alignment
    __shared__ float sdiag[64], srmax[64], dinv[64], ksl[128];
    const int tid = threadIdx.x;
    const int m = tid & 127, half = tid >> 7;
    float wreg[DDIM];
    {
        const float4* w4 = (const float4*)(w + m*DDIM);
#pragma unroll
        for (int q = 0; q < 8; ++q) {
            const float4 t = w4[q];
            wreg[q*4+0]=t.x; wreg[q*4+1]=t.y; wreg[q*4+2]=t.z; wreg[q*4+3]=t.w;
        }
    }
    const int bh = blockIdx.x >> 6, blk = blockIdx.x & 63;
    const int b = bh >> 3, h = bh & 7;
    const unsigned gu = *((const unsigned*)(ws + GMAX_OFF));
    const float gm = (gu & 0x80000000u) ? __uint_as_float(gu & 0x7fffffffu)
                                        : __uint_as_float(~gu);
    const float alpha = __expf(-gm);
    const float* ctxr = ws + CTXR_OFF + bh*4096;
    const float* vsg  = ws + VSUM_OFF + bh*32;
    for (int g = tid; g < 4096; g += 256) {
        const int c = g >> 9, mm2 = (g >> 2) & 127, j = g & 3;
        ctx_s[c*516 + mm2*4 + j] = RATIO*(alpha*ctxr[g] + EPSF*vsg[c*4 + j]);
    }
    if (tid < 128) ksl[tid] = RATIO*(alpha*ws[KSUMR_OFF + bh*MM + tid] + EPSF*(float)LL);
    const float* rmaxg = ws + RMAX_OFF;
    const float* diagg = ws + DIAG_OFF;
    for (int tile = 0; tile < 2; ++tile) {
        const int lbase = blk*128 + tile*64;
        const int n0 = b*LL + lbase;
        __syncthreads();
        // stage 64 feature rows + diag/rmax
#pragma unroll
        for (int p = 0; p < 8; ++p) {
            const int i = tid + p*256;
            if (i < 512)       { const int lr = i >> 3, d = i & 7;
                                 sf[lr][d] = kk0[(n0+lr)*64 + h*8 + d] * DN; }
            else if (i < 2048) { const int jn = i - 512; const int lr = jn/24;
                                 const int d2 = jn - lr*24;
                                 sf[lr][8 + d2] = kk1[(n0+lr)*192 + h*24 + d2] * DN; }
        }
        if (tid < 64)       sdiag[tid]    = diagg[(n0+tid)*8 + h];
        else if (tid < 128) srmax[tid-64] = rmaxg[(n0+tid-64)*8 + h];
        __syncthreads();
        // phase A: Qp for 64 rows -> qpT (full unroll: R6's unroll-2 cost +60us)
#pragma unroll
        for (int r4 = 0; r4 < 8; ++r4) {
            float q4[4];
#pragma unroll
            for (int k = 0; k < 4; ++k) {
                const int row = half*32 + r4*4 + k;
                const float4* f4 = (const float4*)&sf[row][0];
                float dd = 0.f;
#pragma unroll
                for (int q = 0; q < 8; ++q) {
                    const float4 qv = f4[q];
                    dd = fmaf(qv.x, wreg[q*4+0], dd);
                    dd = fmaf(qv.y, wreg[q*4+1], dd);
                    dd = fmaf(qv.z, wreg[q*4+2], dd);
                    dd = fmaf(qv.w, wreg[q*4+3], dd);
                }
                q4[k] = RATIO*(__expf(dd - sdiag[row] - srmax[row]) + EPSF);
            }
            *(float4*)&qpT[m*68 + half*32 + r4*4] = make_float4(q4[0],q4[1],q4[2],q4[3]);
        }
        __syncthreads();
        // phase B: D_inv
        {
            const int row = tid >> 2, mq = tid & 3;
            float ssum = 0.f;
#pragma unroll
            for (int i = 0; i < 32; ++i) {
                const int mm2 = mq*32 + i;
                ssum = fmaf(qpT[mm2*68 + row], ksl[mm2], ssum);
            }
            ssum += __shfl_xor(ssum, 1);
            ssum += __shfl_xor(ssum, 2);
            if (mq == 0) dinv[row] = 1.f/ssum;
        }
        __syncthreads();
        // phase C: out = (qp . ctx) * dinv, register-tiled
        {
            const int c = tid & 7, mh = (tid >> 3) & 1, rg = tid >> 4;
            float4 a0 = {0,0,0,0}, a1 = {0,0,0,0}, a2 = {0,0,0,0}, a3 = {0,0,0,0};
            const float4* cx = (const float4*)&ctx_s[c*516];
            const int mstart = mh*64;
#pragma unroll 8
            for (int i = 0; i < 64; ++i) {
                const int mm2 = mstart + i;
                const float4 cv = cx[mm2];
                const float4 qv = *(const float4*)&qpT[mm2*68 + rg*4];
                a0.x = fmaf(qv.x, cv.x, a0.x); a0.y = fmaf(qv.x, cv.y, a0.y);
                a0.z = fmaf(qv.x, cv.z, a0.z); a0.w = fmaf(qv.x, cv.w, a0.w);
                a1.x = fmaf(qv.y, cv.x, a1.x); a1.y = fmaf(qv.y, cv.y, a1.y);
                a1.z = fmaf(qv.y, cv.z, a1.z); a1.w = fmaf(qv.y, cv.w, a1.w);
                a2.x = fmaf(qv.z, cv.x, a2.x); a2.y = fmaf(qv.z, cv.y, a2.y);
                a2.z = fmaf(qv.z, cv.z, a2.z); a2.w = fmaf(qv.z, cv.w, a2.w);
                a3.x = fmaf(qv.w, cv.x, a3.x); a3.y = fmaf(qv.w, cv.y, a3.y);
                a3.z = fmaf(qv.w, cv.z, a3.z); a3.w = fmaf(qv.w, cv.w, a3.w);
            }
            a0.x += __shfl_xor(a0.x, 8); a0.y += __shfl_xor(a0.y, 8);
            a0.z += __shfl_xor(a0.z, 8); a0.w += __shfl_xor(a0.w, 8);
            a1.x += __shfl_xor(a1.x, 8); a1.y += __shfl_xor(a1.y, 8);
            a1.z += __shfl_xor(a1.z, 8); a1.w += __shfl_xor(a1.w, 8);
            a2.x += __shfl_xor(a2.x, 8); a2.y += __shfl_xor(a2.y, 8);
            a2.z += __shfl_xor(a2.z, 8); a2.w += __shfl_xor(a2.w, 8);
            a3.x += __shfl_xor(a3.x, 8); a3.y += __shfl_xor(a3.y, 8);
            a3.z += __shfl_xor(a3.z, 8); a3.w += __shfl_xor(a3.w, 8);
            const float4 s0 = mh ? a2 : a0;
            const float4 s1 = mh ? a3 : a1;
            const int lr0 = rg*4 + mh*2;
#pragma unroll
            for (int k = 0; k < 2; ++k) {
                const float4 sv4 = k ? s1 : s0;
                const int lr = lr0 + k;
                const float dv = dinv[lr];
                const int n = n0 + lr;
                const int base = n*64 + h*8 + c;
                out[base] = sv4.x * dv;
                float* o1 = out + NN*64 + base*3;
                o1[0] = sv4.y * dv;
                o1[1] = sv4.z * dv;
                o1[2] = sv4.w * dv;
            }
        }
    }
}

extern "C" void kernel_launch(void* const* d_in, const int* in_sizes, int n_in,
                              void* d_out, int out_size, void* d_ws, size_t ws_size,
                              hipStream_t stream) {
    const float* v0 = (const float*)d_in[0];
    const float* v1 = (const float*)d_in[1];
    const float* k0 = (const float*)d_in[2];
    const float* k1 = (const float*)d_in[3];
    const float* w  = (const float*)d_in[6];
    float* out = (float*)d_out;
    float* ws  = (float*)d_ws;
    hipMemsetAsync(ws, 0, (size_t)ZERO_FLOATS*sizeof(float), stream);
    k_ctx1<<<2048, 256, 0, stream>>>(k0, k1, v0, v1, w, ws);
    k_out <<<2048, 256, 0, stream>>>(k0, k1, w, ws, out);
}

// Round 10
// 321.482 us; speedup vs baseline: 5.8208x; 1.0027x over previous
//
#include <hip/hip_runtime.h>

#define BB 4
#define HH 8
#define LL 8192
#define NN (BB*LL)
#define DDIM 32
#define MM 128

// ws layout (float offsets)
#define CTXR_OFF 0                          // 32*8*128*4 = 131072
#define KSUMR_OFF (CTXR_OFF + 32*8*MM*4)    // 4096
#define VSUM_OFF  (KSUMR_OFF + 32*MM)       // 1024
#define GMAX_OFF  (VSUM_OFF + 32*32)        // 1
#define ZERO_FLOATS (GMAX_OFF + 1)

#define DN 0.42044820762685725f             // 32^-0.25
#define RATIO 0.08838834764831845f          // 128^-0.5
#define EPSF 1e-4f

// ------- k1: raw ctx/ksum/vsum/gmax. NO LDS in main loop: all row data via
// wave-uniform global loads (scalar path), kp/acc in registers. Each wave
// independently owns (bh, half-of-m, 128 rows). One barrier total.
// R9 bug fixed: vsum atomic must use PACKED (c*4+j) slot, matching k_out's
// vsg[c*4+j] consumption (eps*L is ~O(alpha*ksum) here, so it matters).
__global__ __launch_bounds__(256, 2) void k_ctx1(const float* __restrict__ kk0,
                                                 const float* __restrict__ kk1,
                                                 const float* __restrict__ v0,
                                                 const float* __restrict__ v1,
                                                 const float* __restrict__ w,
                                                 float* __restrict__ ws) {
    __shared__ float red[2][64][34];
    const int tid = threadIdx.x;
    const int lane = tid & 63;
    const int wid  = __builtin_amdgcn_readfirstlane(tid >> 6);
    const int half = wid & 1, rgrp = wid >> 1;
    const int m = half*64 + lane;
    const int bh = blockIdx.x >> 5, chunk = blockIdx.x & 31;
    const int b = bh >> 3, h = bh & 7;
    const int n0 = b*LL + chunk*256 + rgrp*128;
    float wreg[32];                           // w * DN (DN folded into w)
    {
        const float4* w4 = (const float4*)(w + m*DDIM);
#pragma unroll
        for (int q = 0; q < 8; ++q) {
            const float4 t = w4[q];
            wreg[q*4+0]=t.x*DN; wreg[q*4+1]=t.y*DN;
            wreg[q*4+2]=t.z*DN; wreg[q*4+3]=t.w*DN;
        }
    }
    float acc[32];
#pragma unroll
    for (int i = 0; i < 32; ++i) acc[i] = 0.f;
    float ksum_acc = 0.f, vsum_acc = 0.f, wmax = -3.4e38f;
    for (int s = 0; s < 8; ++s) {
        const int nb = n0 + s*16;
        // per-row diag: 4 lanes per row, 8 elems each, in-wave shuffle reduce
        const int dr_ = lane >> 2, dq = lane & 3;
        float diagv;
        {
            const int n = nb + dr_;
            float4 da, db;
            if (dq == 0) {
                da = *(const float4*)(kk0 + (size_t)n*64 + h*8);
                db = *(const float4*)(kk0 + (size_t)n*64 + h*8 + 4);
            } else {
                const float* bp = kk1 + (size_t)n*192 + h*24 + (dq-1)*8;
                da = *(const float4*)bp; db = *(const float4*)(bp + 4);
            }
            float ss = da.x*da.x+da.y*da.y+da.z*da.z+da.w*da.w
                     + db.x*db.x+db.y*db.y+db.z*db.z+db.w*db.w;
            ss += __shfl_xor(ss, 1); ss += __shfl_xor(ss, 2);
            diagv = 0.5f*DN*DN*ss;
        }
        // vsum (half0 waves only): 2 lane-groups x 8 rows, elem = lane&31
        if (half == 0) {
            const int ve = lane & 31, vg = lane >> 5;
#pragma unroll
            for (int rr = 0; rr < 8; ++rr) {
                const int n = nb + vg*8 + rr;
                vsum_acc += (ve < 8) ? v0[(size_t)n*64 + h*8 + ve]
                                     : v1[(size_t)n*192 + h*24 + (ve-8)];
            }
        }
#pragma unroll 1
        for (int r = 0; r < 16; ++r) {
            const int n = nb + r;
            const float dg = __uint_as_float(
                __builtin_amdgcn_readlane(__float_as_uint(diagv), r*4));
            const float4 f0 = *(const float4*)(kk0 + (size_t)n*64 + h*8);
            const float4 f1 = *(const float4*)(kk0 + (size_t)n*64 + h*8 + 4);
            const float4* g4 = (const float4*)(kk1 + (size_t)n*192 + h*24);
            float dd0 =       f0.x*wreg[0];        float dd1 = f0.y*wreg[1];
            dd0 = fmaf(f0.z, wreg[2], dd0);  dd1 = fmaf(f0.w, wreg[3], dd1);
            dd0 = fmaf(f1.x, wreg[4], dd0);  dd1 = fmaf(f1.y, wreg[5], dd1);
            dd0 = fmaf(f1.z, wreg[6], dd0);  dd1 = fmaf(f1.w, wreg[7], dd1);
#pragma unroll
            for (int gq = 0; gq < 6; ++gq) {
                const float4 g = g4[gq];
                dd0 = fmaf(g.x, wreg[8+gq*4+0], dd0);
                dd1 = fmaf(g.y, wreg[8+gq*4+1], dd1);
                dd0 = fmaf(g.z, wreg[8+gq*4+2], dd0);
                dd1 = fmaf(g.w, wreg[8+gq*4+3], dd1);
            }
            const float dd = dd0 + dd1;
            wmax = fmaxf(wmax, dd);
            const float kp = __expf(dd - dg);
            ksum_acc += kp;
            const float4 a0 = *(const float4*)(v0 + (size_t)n*64 + h*8);
            const float4 a1 = *(const float4*)(v0 + (size_t)n*64 + h*8 + 4);
            const float4* b4 = (const float4*)(v1 + (size_t)n*192 + h*24);
            acc[0]  = fmaf(kp,a0.x,acc[0]);   acc[4]  = fmaf(kp,a0.y,acc[4]);
            acc[8]  = fmaf(kp,a0.z,acc[8]);   acc[12] = fmaf(kp,a0.w,acc[12]);
            acc[16] = fmaf(kp,a1.x,acc[16]);  acc[20] = fmaf(kp,a1.y,acc[20]);
            acc[24] = fmaf(kp,a1.z,acc[24]);  acc[28] = fmaf(kp,a1.w,acc[28]);
            {   // v1 elems e -> acc[(e/3)*4 + 1 + e%3]
                float4 g;
                g = b4[0];
                acc[1]=fmaf(kp,g.x,acc[1]);  acc[2]=fmaf(kp,g.y,acc[2]);
                acc[3]=fmaf(kp,g.z,acc[3]);  acc[5]=fmaf(kp,g.w,acc[5]);
                g = b4[1];
                acc[6]=fmaf(kp,g.x,acc[6]);  acc[7]=fmaf(kp,g.y,acc[7]);
                acc[9]=fmaf(kp,g.z,acc[9]);  acc[10]=fmaf(kp,g.w,acc[10]);
                g = b4[2];
                acc[11]=fmaf(kp,g.x,acc[11]); acc[13]=fmaf(kp,g.y,acc[13]);
                acc[14]=fmaf(kp,g.z,acc[14]); acc[15]=fmaf(kp,g.w,acc[15]);
                g = b4[3];
                acc[17]=fmaf(kp,g.x,acc[17]); acc[18]=fmaf(kp,g.y,acc[18]);
                acc[19]=fmaf(kp,g.z,acc[19]); acc[21]=fmaf(kp,g.w,acc[21]);
                g = b4[4];
                acc[22]=fmaf(kp,g.x,acc[22]); acc[23]=fmaf(kp,g.y,acc[23]);
                acc[25]=fmaf(kp,g.z,acc[25]); acc[26]=fmaf(kp,g.w,acc[26]);
                g = b4[5];
                acc[27]=fmaf(kp,g.x,acc[27]); acc[29]=fmaf(kp,g.y,acc[29]);
                acc[30]=fmaf(kp,g.z,acc[30]); acc[31]=fmaf(kp,g.w,acc[31]);
            }
        }
    }
    // combine rgrp pairs in LDS, then one atomic set per (m,c,e) per block
    if (rgrp == 1) {
#pragma unroll
        for (int i = 0; i < 32; ++i) red[half][lane][i] = acc[i];
        red[half][lane][32] = ksum_acc;
        red[half][lane][33] = vsum_acc;
    }
    __syncthreads();
    if (rgrp == 0) {
#pragma unroll
        for (int i = 0; i < 32; ++i) acc[i] += red[half][lane][i];
        ksum_acc += red[half][lane][32];
        vsum_acc += red[half][lane][33];
        float* ctxr = ws + CTXR_OFF;
#pragma unroll
        for (int c = 0; c < 8; ++c)
#pragma unroll
            for (int j = 0; j < 4; ++j)
                atomicAdd(&ctxr[((bh*8 + c)*MM + m)*4 + j], acc[c*4+j]);
        atomicAdd(ws + KSUMR_OFF + bh*MM + m, ksum_acc);
        if (half == 0) {
            const int ve = lane & 31;
            const int packed = (ve < 8) ? ve*4
                                        : ((ve-8)/3)*4 + 1 + (ve-8)%3;
            atomicAdd(ws + VSUM_OFF + bh*32 + packed, vsum_acc);
        }
    }
#pragma unroll
    for (int off = 32; off; off >>= 1) wmax = fmaxf(wmax, __shfl_xor(wmax, off, 64));
    if (lane == 0) {
        unsigned u = __float_as_uint(wmax);
        u = (u & 0x80000000u) ? ~u : (u | 0x80000000u);
        atomicMax((unsigned*)(ws + GMAX_OFF), u);
    }
}

// ------- k3: finalize ctx/ksum, dd from uniform global loads (no sf LDS),
// in-kernel diag + rowmax, D_inv, readout.
__global__ __launch_bounds__(256) void k_out(const float* __restrict__ kk0,
                                             const float* __restrict__ kk1,
                                             const float* __restrict__ w,
                                             const float* __restrict__ ws,
                                             float* __restrict__ out) {
    __shared__ float ctx_s[8*516];
    __shared__ __align__(16) float qpT[128*68];   // [m][row<64], pad 68
    __shared__ __align__(16) float sdiag[64];
    __shared__ __align__(16) float srmax[64];
    __shared__ float dinv[64], ksl[128];
    const int tid = threadIdx.x;
    const int m = tid & 127, half = tid >> 7;
    float wreg[32];                                // w * DN
    {
        const float4* w4 = (const float4*)(w + m*DDIM);
#pragma unroll
        for (int q = 0; q < 8; ++q) {
            const float4 t = w4[q];
            wreg[q*4+0]=t.x*DN; wreg[q*4+1]=t.y*DN;
            wreg[q*4+2]=t.z*DN; wreg[q*4+3]=t.w*DN;
        }
    }
    const int bh = blockIdx.x >> 6, blk = blockIdx.x & 63;
    const int b = bh >> 3, h = bh & 7;
    const unsigned gu = *((const unsigned*)(ws + GMAX_OFF));
    const float gm = (gu & 0x80000000u) ? __uint_as_float(gu & 0x7fffffffu)
                                        : __uint_as_float(~gu);
    const float alpha = __expf(-gm);
    const float* ctxr = ws + CTXR_OFF + bh*4096;
    const float* vsg  = ws + VSUM_OFF + bh*32;
    for (int g = tid; g < 4096; g += 256) {
        const int c = g >> 9, mm2 = (g >> 2) & 127, j = g & 3;
        ctx_s[c*516 + mm2*4 + j] = RATIO*(alpha*ctxr[g] + EPSF*vsg[c*4 + j]);
    }
    if (tid < 128) ksl[tid] = RATIO*(alpha*ws[KSUMR_OFF + bh*MM + tid] + EPSF*(float)LL);
    for (int tile = 0; tile < 2; ++tile) {
        const int lbase = blk*128 + tile*64;
        const int n0 = b*LL + lbase;
        __syncthreads();
        // diag pass: 4 threads per row, 8 elems each, from global
        {
            const int dr_ = tid >> 2, dq = tid & 3;
            const int n = n0 + dr_;
            float4 da, db;
            if (dq == 0) {
                da = *(const float4*)(kk0 + (size_t)n*64 + h*8);
                db = *(const float4*)(kk0 + (size_t)n*64 + h*8 + 4);
            } else {
                const float* bp = kk1 + (size_t)n*192 + h*24 + (dq-1)*8;
                da = *(const float4*)bp; db = *(const float4*)(bp + 4);
            }
            float ss = da.x*da.x+da.y*da.y+da.z*da.z+da.w*da.w
                     + db.x*db.x+db.y*db.y+db.z*db.z+db.w*db.w;
            ss += __shfl_xor(ss, 1); ss += __shfl_xor(ss, 2);
            if (dq == 0) sdiag[dr_] = 0.5f*DN*DN*ss;
        }
        // phase A: raw dd for my m over 32 rows (uniform global feats) -> qpT + regs
        float ddreg[32];
#pragma unroll
        for (int r4 = 0; r4 < 8; ++r4) {
#pragma unroll
            for (int k = 0; k < 4; ++k) {
                const int n = n0 + half*32 + r4*4 + k;
                const float4 f0 = *(const float4*)(kk0 + (size_t)n*64 + h*8);
                const float4 f1 = *(const float4*)(kk0 + (size_t)n*64 + h*8 + 4);
                const float4* g4 = (const float4*)(kk1 + (size_t)n*192 + h*24);
                float dd0 =       f0.x*wreg[0];       float dd1 = f0.y*wreg[1];
                dd0 = fmaf(f0.z, wreg[2], dd0);  dd1 = fmaf(f0.w, wreg[3], dd1);
                dd0 = fmaf(f1.x, wreg[4], dd0);  dd1 = fmaf(f1.y, wreg[5], dd1);
                dd0 = fmaf(f1.z, wreg[6], dd0);  dd1 = fmaf(f1.w, wreg[7], dd1);
#pragma unroll
                for (int gq = 0; gq < 6; ++gq) {
                    const float4 g = g4[gq];
                    dd0 = fmaf(g.x, wreg[8+gq*4+0], dd0);
                    dd1 = fmaf(g.y, wreg[8+gq*4+1], dd1);
                    dd0 = fmaf(g.z, wreg[8+gq*4+2], dd0);
                    dd1 = fmaf(g.w, wreg[8+gq*4+3], dd1);
                }
                ddreg[r4*4+k] = dd0 + dd1;
            }
            *(float4*)&qpT[m*68 + half*32 + r4*4] =
                make_float4(ddreg[r4*4+0], ddreg[r4*4+1], ddreg[r4*4+2], ddreg[r4*4+3]);
        }
        __syncthreads();
        // A2: per-row max over m (reference rmax = max_m dd, exact)
        {
            const int row = tid >> 2, mq = tid & 3;
            float mx = -3.4e38f;
#pragma unroll
            for (int i = 0; i < 32; ++i)
                mx = fmaxf(mx, qpT[(mq*32 + i)*68 + row]);
            mx = fmaxf(mx, __shfl_xor(mx, 1));
            mx = fmaxf(mx, __shfl_xor(mx, 2));
            if (mq == 0) srmax[row] = mx;
        }
        __syncthreads();
        // A3: qp = RATIO*(exp(dd - diag - rmax) + eps) -> qpT
#pragma unroll
        for (int r4 = 0; r4 < 8; ++r4) {
            const float4 sd = *(const float4*)&sdiag[half*32 + r4*4];
            const float4 sm = *(const float4*)&srmax[half*32 + r4*4];
            float4 qp;
            qp.x = RATIO*(__expf(ddreg[r4*4+0] - sd.x - sm.x) + EPSF);
            qp.y = RATIO*(__expf(ddreg[r4*4+1] - sd.y - sm.y) + EPSF);
            qp.z = RATIO*(__expf(ddreg[r4*4+2] - sd.z - sm.z) + EPSF);
            qp.w = RATIO*(__expf(ddreg[r4*4+3] - sd.w - sm.w) + EPSF);
            *(float4*)&qpT[m*68 + half*32 + r4*4] = qp;
        }
        __syncthreads();
        // phase B: D_inv
        {
            const int row = tid >> 2, mq = tid & 3;
            float ssum = 0.f;
#pragma unroll
            for (int i = 0; i < 32; ++i) {
                const int mm2 = mq*32 + i;
                ssum = fmaf(qpT[mm2*68 + row], ksl[mm2], ssum);
            }
            ssum += __shfl_xor(ssum, 1);
            ssum += __shfl_xor(ssum, 2);
            if (mq == 0) dinv[row] = 1.f/ssum;
        }
        __syncthreads();
        // phase C: out = (qp . ctx) * dinv, register-tiled
        {
            const int c = tid & 7, mh = (tid >> 3) & 1, rg = tid >> 4;
            float4 a0 = {0,0,0,0}, a1 = {0,0,0,0}, a2 = {0,0,0,0}, a3 = {0,0,0,0};
            const float4* cx = (const float4*)&ctx_s[c*516];
            const int mstart = mh*64;
#pragma unroll 8
            for (int i = 0; i < 64; ++i) {
                const int mm2 = mstart + i;
                const float4 cv = cx[mm2];
                const float4 qv = *(const float4*)&qpT[mm2*68 + rg*4];
                a0.x = fmaf(qv.x, cv.x, a0.x); a0.y = fmaf(qv.x, cv.y, a0.y);
                a0.z = fmaf(qv.x, cv.z, a0.z); a0.w = fmaf(qv.x, cv.w, a0.w);
                a1.x = fmaf(qv.y, cv.x, a1.x); a1.y = fmaf(qv.y, cv.y, a1.y);
                a1.z = fmaf(qv.y, cv.z, a1.z); a1.w = fmaf(qv.y, cv.w, a1.w);
                a2.x = fmaf(qv.z, cv.x, a2.x); a2.y = fmaf(qv.z, cv.y, a2.y);
                a2.z = fmaf(qv.z, cv.z, a2.z); a2.w = fmaf(qv.z, cv.w, a2.w);
                a3.x = fmaf(qv.w, cv.x, a3.x); a3.y = fmaf(qv.w, cv.y, a3.y);
                a3.z = fmaf(qv.w, cv.z, a3.z); a3.w = fmaf(qv.w, cv.w, a3.w);
            }
            a0.x += __shfl_xor(a0.x, 8); a0.y += __shfl_xor(a0.y, 8);
            a0.z += __shfl_xor(a0.z, 8); a0.w += __shfl_xor(a0.w, 8);
            a1.x += __shfl_xor(a1.x, 8); a1.y += __shfl_xor(a1.y, 8);
            a1.z += __shfl_xor(a1.z, 8); a1.w += __shfl_xor(a1.w, 8);
            a2.x += __shfl_xor(a2.x, 8); a2.y += __shfl_xor(a2.y, 8);
            a2.z += __shfl_xor(a2.z, 8); a2.w += __shfl_xor(a2.w, 8);
            a3.x += __shfl_xor(a3.x, 8); a3.y += __shfl_xor(a3.y, 8);
            a3.z += __shfl_xor(a3.z, 8); a3.w += __shfl_xor(a3.w, 8);
            const float4 s0 = mh ? a2 : a0;
            const float4 s1 = mh ? a3 : a1;
            const int lr0 = rg*4 + mh*2;
#pragma unroll
            for (int k = 0; k < 2; ++k) {
                const float4 sv4 = k ? s1 : s0;
                const int lr = lr0 + k;
                const float dv = dinv[lr];
                const int n = n0 + lr;
                const int base = n*64 + h*8 + c;
                out[base] = sv4.x * dv;
                float* o1 = out + NN*64 + base*3;
                o1[0] = sv4.y * dv;
                o1[1] = sv4.z * dv;
                o1[2] = sv4.w * dv;
            }
        }
    }
}

extern "C" void kernel_launch(void* const* d_in, const int* in_sizes, int n_in,
                              void* d_out, int out_size, void* d_ws, size_t ws_size,
                              hipStream_t stream) {
    const float* v0 = (const float*)d_in[0];
    const float* v1 = (const float*)d_in[1];
    const float* k0 = (const float*)d_in[2];
    const float* k1 = (const float*)d_in[3];
    const float* w  = (const float*)d_in[6];
    float* out = (float*)d_out;
    float* ws  = (float*)d_ws;
    hipMemsetAsync(ws, 0, (size_t)ZERO_FLOATS*sizeof(float), stream);
    k_ctx1<<<1024, 256, 0, stream>>>(k0, k1, v0, v1, w, ws);
    k_out <<<2048, 256, 0, stream>>>(k0, k1, w, ws, out);
}

// Round 11
// 229.634 us; speedup vs baseline: 8.1490x; 1.4000x over previous
//
#include <hip/hip_runtime.h>

#define BB 4
#define HH 8
#define LL 8192
#define NN (BB*LL)
#define DDIM 32
#define MM 128

// ws layout (float offsets)
#define CTXR_OFF 0                          // 32*8*128*4 = 131072
#define KSUMR_OFF (CTXR_OFF + 32*8*MM*4)    // 4096
#define VSUM_OFF  (KSUMR_OFF + 32*MM)       // 1024
#define GMAX_OFF  (VSUM_OFF + 32*32)        // 1
#define ZERO_FLOATS (GMAX_OFF + 1)

#define DN 0.42044820762685725f             // 32^-0.25
#define RATIO 0.08838834764831845f          // 128^-0.5
#define EPSF 1e-4f

// ------- k1: raw ctx/ksum/vsum/gmax (unchanged from R10: passed, ~110-130us)
__global__ __launch_bounds__(256, 2) void k_ctx1(const float* __restrict__ kk0,
                                                 const float* __restrict__ kk1,
                                                 const float* __restrict__ v0,
                                                 const float* __restrict__ v1,
                                                 const float* __restrict__ w,
                                                 float* __restrict__ ws) {
    __shared__ float red[2][64][34];
    const int tid = threadIdx.x;
    const int lane = tid & 63;
    const int wid  = __builtin_amdgcn_readfirstlane(tid >> 6);
    const int half = wid & 1, rgrp = wid >> 1;
    const int m = half*64 + lane;
    const int bh = blockIdx.x >> 5, chunk = blockIdx.x & 31;
    const int b = bh >> 3, h = bh & 7;
    const int n0 = b*LL + chunk*256 + rgrp*128;
    float wreg[32];                           // w * DN (DN folded into w)
    {
        const float4* w4 = (const float4*)(w + m*DDIM);
#pragma unroll
        for (int q = 0; q < 8; ++q) {
            const float4 t = w4[q];
            wreg[q*4+0]=t.x*DN; wreg[q*4+1]=t.y*DN;
            wreg[q*4+2]=t.z*DN; wreg[q*4+3]=t.w*DN;
        }
    }
    float acc[32];
#pragma unroll
    for (int i = 0; i < 32; ++i) acc[i] = 0.f;
    float ksum_acc = 0.f, vsum_acc = 0.f, wmax = -3.4e38f;
    for (int s = 0; s < 8; ++s) {
        const int nb = n0 + s*16;
        const int dr_ = lane >> 2, dq = lane & 3;
        float diagv;
        {
            const int n = nb + dr_;
            float4 da, db;
            if (dq == 0) {
                da = *(const float4*)(kk0 + (size_t)n*64 + h*8);
                db = *(const float4*)(kk0 + (size_t)n*64 + h*8 + 4);
            } else {
                const float* bp = kk1 + (size_t)n*192 + h*24 + (dq-1)*8;
                da = *(const float4*)bp; db = *(const float4*)(bp + 4);
            }
            float ss = da.x*da.x+da.y*da.y+da.z*da.z+da.w*da.w
                     + db.x*db.x+db.y*db.y+db.z*db.z+db.w*db.w;
            ss += __shfl_xor(ss, 1); ss += __shfl_xor(ss, 2);
            diagv = 0.5f*DN*DN*ss;
        }
        if (half == 0) {
            const int ve = lane & 31, vg = lane >> 5;
#pragma unroll
            for (int rr = 0; rr < 8; ++rr) {
                const int n = nb + vg*8 + rr;
                vsum_acc += (ve < 8) ? v0[(size_t)n*64 + h*8 + ve]
                                     : v1[(size_t)n*192 + h*24 + (ve-8)];
            }
        }
#pragma unroll 1
        for (int r = 0; r < 16; ++r) {
            const int n = nb + r;
            const float dg = __uint_as_float(
                __builtin_amdgcn_readlane(__float_as_uint(diagv), r*4));
            const float4 f0 = *(const float4*)(kk0 + (size_t)n*64 + h*8);
            const float4 f1 = *(const float4*)(kk0 + (size_t)n*64 + h*8 + 4);
            const float4* g4 = (const float4*)(kk1 + (size_t)n*192 + h*24);
            float dd0 =       f0.x*wreg[0];        float dd1 = f0.y*wreg[1];
            dd0 = fmaf(f0.z, wreg[2], dd0);  dd1 = fmaf(f0.w, wreg[3], dd1);
            dd0 = fmaf(f1.x, wreg[4], dd0);  dd1 = fmaf(f1.y, wreg[5], dd1);
            dd0 = fmaf(f1.z, wreg[6], dd0);  dd1 = fmaf(f1.w, wreg[7], dd1);
#pragma unroll
            for (int gq = 0; gq < 6; ++gq) {
                const float4 g = g4[gq];
                dd0 = fmaf(g.x, wreg[8+gq*4+0], dd0);
                dd1 = fmaf(g.y, wreg[8+gq*4+1], dd1);
                dd0 = fmaf(g.z, wreg[8+gq*4+2], dd0);
                dd1 = fmaf(g.w, wreg[8+gq*4+3], dd1);
            }
            const float dd = dd0 + dd1;
            wmax = fmaxf(wmax, dd);
            const float kp = __expf(dd - dg);
            ksum_acc += kp;
            const float4 a0 = *(const float4*)(v0 + (size_t)n*64 + h*8);
            const float4 a1 = *(const float4*)(v0 + (size_t)n*64 + h*8 + 4);
            const float4* b4 = (const float4*)(v1 + (size_t)n*192 + h*24);
            acc[0]  = fmaf(kp,a0.x,acc[0]);   acc[4]  = fmaf(kp,a0.y,acc[4]);
            acc[8]  = fmaf(kp,a0.z,acc[8]);   acc[12] = fmaf(kp,a0.w,acc[12]);
            acc[16] = fmaf(kp,a1.x,acc[16]);  acc[20] = fmaf(kp,a1.y,acc[20]);
            acc[24] = fmaf(kp,a1.z,acc[24]);  acc[28] = fmaf(kp,a1.w,acc[28]);
            {
                float4 g;
                g = b4[0];
                acc[1]=fmaf(kp,g.x,acc[1]);  acc[2]=fmaf(kp,g.y,acc[2]);
                acc[3]=fmaf(kp,g.z,acc[3]);  acc[5]=fmaf(kp,g.w,acc[5]);
                g = b4[1];
                acc[6]=fmaf(kp,g.x,acc[6]);  acc[7]=fmaf(kp,g.y,acc[7]);
                acc[9]=fmaf(kp,g.z,acc[9]);  acc[10]=fmaf(kp,g.w,acc[10]);
                g = b4[2];
                acc[11]=fmaf(kp,g.x,acc[11]); acc[13]=fmaf(kp,g.y,acc[13]);
                acc[14]=fmaf(kp,g.z,acc[14]); acc[15]=fmaf(kp,g.w,acc[15]);
                g = b4[3];
                acc[17]=fmaf(kp,g.x,acc[17]); acc[18]=fmaf(kp,g.y,acc[18]);
                acc[19]=fmaf(kp,g.z,acc[19]); acc[21]=fmaf(kp,g.w,acc[21]);
                g = b4[4];
                acc[22]=fmaf(kp,g.x,acc[22]); acc[23]=fmaf(kp,g.y,acc[23]);
                acc[25]=fmaf(kp,g.z,acc[25]); acc[26]=fmaf(kp,g.w,acc[26]);
                g = b4[5];
                acc[27]=fmaf(kp,g.x,acc[27]); acc[29]=fmaf(kp,g.y,acc[29]);
                acc[30]=fmaf(kp,g.z,acc[30]); acc[31]=fmaf(kp,g.w,acc[31]);
            }
        }
    }
    if (rgrp == 1) {
#pragma unroll
        for (int i = 0; i < 32; ++i) red[half][lane][i] = acc[i];
        red[half][lane][32] = ksum_acc;
        red[half][lane][33] = vsum_acc;
    }
    __syncthreads();
    if (rgrp == 0) {
#pragma unroll
        for (int i = 0; i < 32; ++i) acc[i] += red[half][lane][i];
        ksum_acc += red[half][lane][32];
        vsum_acc += red[half][lane][33];
        float* ctxr = ws + CTXR_OFF;
#pragma unroll
        for (int c = 0; c < 8; ++c)
#pragma unroll
            for (int j = 0; j < 4; ++j)
                atomicAdd(&ctxr[((bh*8 + c)*MM + m)*4 + j], acc[c*4+j]);
        atomicAdd(ws + KSUMR_OFF + bh*MM + m, ksum_acc);
        if (half == 0) {
            const int ve = lane & 31;
            const int packed = (ve < 8) ? ve*4
                                        : ((ve-8)/3)*4 + 1 + (ve-8)%3;
            atomicAdd(ws + VSUM_OFF + bh*32 + packed, vsum_acc);
        }
    }
#pragma unroll
    for (int off = 32; off; off >>= 1) wmax = fmaxf(wmax, __shfl_xor(wmax, off, 64));
    if (lane == 0) {
        unsigned u = __float_as_uint(wmax);
        u = (u & 0x80000000u) ? ~u : (u | 0x80000000u);
        atomicMax((unsigned*)(ws + GMAX_OFF), u);
    }
}

// ------- k3 REWRITE: row-per-lane. Lane owns one (n,h) output row; K in regs;
// loop over m reading w-row + ctx-row as LDS broadcasts (uniform per m,
// conflict-free). rmax factored out: num = e^-mx*S1 + eps*S0, den likewise
// (Qp's RATIO cancels). Zero barriers in main loop, no qpT transpose.
__global__ __launch_bounds__(256, 2) void k_out(const float* __restrict__ kk0,
                                                const float* __restrict__ kk1,
                                                const float* __restrict__ w,
                                                const float* __restrict__ ws,
                                                float* __restrict__ out) {
    __shared__ float ctx_s[128*36];   // [m][p], pad 36 (b128-aligned rows)
    __shared__ float wlds[128*36];    // [m][d]*DN, pad 36
    __shared__ float ksl[128];
    __shared__ __align__(16) float sS0[32];
    __shared__ float sK0;
    const int tid = threadIdx.x;
    const int bh = blockIdx.x >> 5, chunk = blockIdx.x & 31;
    const int b = bh >> 3, h = bh & 7;
    const unsigned gu = *((const unsigned*)(ws + GMAX_OFF));
    const float gm = (gu & 0x80000000u) ? __uint_as_float(gu & 0x7fffffffu)
                                        : __uint_as_float(~gu);
    const float alpha = __expf(-gm);
    // stage ctx_s[m][p] = RATIO*(alpha*ctxr[c][m][j] + eps*vsg[p]), p=c*4+j
    const float4* ctxr4 = (const float4*)(ws + CTXR_OFF) + (size_t)bh*1024;
    const float* vsg = ws + VSUM_OFF + bh*32;
#pragma unroll
    for (int it = 0; it < 4; ++it) {
        const int i = tid + it*256;          // 0..1023 float4s, [c][m]
        const int c = i >> 7, mm2 = i & 127;
        const float4 q = ctxr4[i];
        const int p0 = c*4;
        ctx_s[mm2*36+p0+0] = RATIO*(alpha*q.x + EPSF*vsg[p0+0]);
        ctx_s[mm2*36+p0+1] = RATIO*(alpha*q.y + EPSF*vsg[p0+1]);
        ctx_s[mm2*36+p0+2] = RATIO*(alpha*q.z + EPSF*vsg[p0+2]);
        ctx_s[mm2*36+p0+3] = RATIO*(alpha*q.w + EPSF*vsg[p0+3]);
    }
    {
        const float4* w4 = (const float4*)w;
#pragma unroll
        for (int it = 0; it < 4; ++it) {
            const int i = tid + it*256;      // [m][q]
            const int mm2 = i >> 3, q = i & 7;
            float4 t = w4[i];
            t.x*=DN; t.y*=DN; t.z*=DN; t.w*=DN;
            *(float4*)&wlds[mm2*36+q*4] = t;
        }
    }
    if (tid < 128) ksl[tid] = RATIO*(alpha*ws[KSUMR_OFF + bh*MM + tid] + EPSF*(float)LL);
    __syncthreads();
    if (tid < 32) {
        float s = 0.f;
#pragma unroll 8
        for (int mm2 = 0; mm2 < 128; ++mm2) s += ctx_s[mm2*36 + tid];
        sS0[tid] = s;
    } else if (tid < 64) {
        const int p2 = tid - 32;
        float s = ksl[p2] + ksl[32+p2] + ksl[64+p2] + ksl[96+p2];
        s += __shfl_xor(s, 1); s += __shfl_xor(s, 2); s += __shfl_xor(s, 4);
        s += __shfl_xor(s, 8); s += __shfl_xor(s, 16);
        if (p2 == 0) sK0 = s;
    }
    __syncthreads();
    // my row
    const int n = b*LL + chunk*256 + tid;
    float K[32];
    {
        const float4 f0 = *(const float4*)(kk0 + (size_t)n*64 + h*8);
        const float4 f1 = *(const float4*)(kk0 + (size_t)n*64 + h*8 + 4);
        K[0]=f0.x; K[1]=f0.y; K[2]=f0.z; K[3]=f0.w;
        K[4]=f1.x; K[5]=f1.y; K[6]=f1.z; K[7]=f1.w;
        const float4* g4p = (const float4*)(kk1 + (size_t)n*192 + h*24);
#pragma unroll
        for (int gq = 0; gq < 6; ++gq) {
            const float4 g = g4p[gq];
            K[8+gq*4+0]=g.x; K[8+gq*4+1]=g.y; K[8+gq*4+2]=g.z; K[8+gq*4+3]=g.w;
        }
    }
    float dg = 0.f;
#pragma unroll
    for (int d = 0; d < 32; ++d) dg = fmaf(K[d], K[d], dg);
    dg *= 0.5f*DN*DN;
    float S1[32];
#pragma unroll
    for (int i = 0; i < 32; ++i) S1[i] = 0.f;
    float den1 = 0.f, mx = -3.4e38f;
#pragma unroll 2
    for (int m2 = 0; m2 < 128; ++m2) {
        const float* wrow = &wlds[m2*36];
        float dd0 = 0.f, dd1 = 0.f;
#pragma unroll
        for (int q = 0; q < 8; ++q) {
            const float4 wv = *(const float4*)&wrow[q*4];
            dd0 = fmaf(K[q*4+0], wv.x, dd0);
            dd1 = fmaf(K[q*4+1], wv.y, dd1);
            dd0 = fmaf(K[q*4+2], wv.z, dd0);
            dd1 = fmaf(K[q*4+3], wv.w, dd1);
        }
        const float dd = dd0 + dd1;
        mx = fmaxf(mx, dd);
        const float E = __expf(dd - dg);
        den1 = fmaf(E, ksl[m2], den1);
        const float* crow = &ctx_s[m2*36];
#pragma unroll
        for (int q = 0; q < 8; ++q) {
            const float4 cv = *(const float4*)&crow[q*4];
            S1[q*4+0] = fmaf(E, cv.x, S1[q*4+0]);
            S1[q*4+1] = fmaf(E, cv.y, S1[q*4+1]);
            S1[q*4+2] = fmaf(E, cv.z, S1[q*4+2]);
            S1[q*4+3] = fmaf(E, cv.w, S1[q*4+3]);
        }
    }
    const float es = __expf(-mx);
    const float dinv = 1.f / fmaf(es, den1, EPSF*sK0);
    float v[32];
#pragma unroll
    for (int q = 0; q < 8; ++q) {
        const float4 s0 = *(const float4*)&sS0[q*4];
        v[q*4+0] = fmaf(es, S1[q*4+0], EPSF*s0.x)*dinv;
        v[q*4+1] = fmaf(es, S1[q*4+1], EPSF*s0.y)*dinv;
        v[q*4+2] = fmaf(es, S1[q*4+2], EPSF*s0.z)*dinv;
        v[q*4+3] = fmaf(es, S1[q*4+3], EPSF*s0.w)*dinv;
    }
    float* o0 = out + (size_t)n*64 + h*8;
    *(float4*)(o0)     = make_float4(v[0],  v[4],  v[8],  v[12]);
    *(float4*)(o0 + 4) = make_float4(v[16], v[20], v[24], v[28]);
    float* o1 = out + (size_t)NN*64 + (size_t)n*192 + h*24;
    *(float4*)(o1 +  0) = make_float4(v[1],  v[2],  v[3],  v[5]);
    *(float4*)(o1 +  4) = make_float4(v[6],  v[7],  v[9],  v[10]);
    *(float4*)(o1 +  8) = make_float4(v[11], v[13], v[14], v[15]);
    *(float4*)(o1 + 12) = make_float4(v[17], v[18], v[19], v[21]);
    *(float4*)(o1 + 16) = make_float4(v[22], v[23], v[25], v[26]);
    *(float4*)(o1 + 20) = make_float4(v[27], v[29], v[30], v[31]);
}

extern "C" void kernel_launch(void* const* d_in, const int* in_sizes, int n_in,
                              void* d_out, int out_size, void* d_ws, size_t ws_size,
                              hipStream_t stream) {
    const float* v0 = (const float*)d_in[0];
    const float* v1 = (const float*)d_in[1];
    const float* k0 = (const float*)d_in[2];
    const float* k1 = (const float*)d_in[3];
    const float* w  = (const float*)d_in[6];
    float* out = (float*)d_out;
    float* ws  = (float*)d_ws;
    hipMemsetAsync(ws, 0, (size_t)ZERO_FLOATS*sizeof(float), stream);
    k_ctx1<<<1024, 256, 0, stream>>>(k0, k1, v0, v1, w, ws);
    k_out <<<1024, 256, 0, stream>>>(k0, k1, w, ws, out);
}